// Round 7
// baseline (224.289 us; speedup 1.0000x reference)
//
#include <hip/hip_runtime.h>
#include <math.h>

#define B 8
#define S 2048
#define D 1024

// ---------------- workspace layout (floats) ----------------
// u_part [16][8][1024] : 0        (written whole by KA, read by KB)
// num    [8][1024]     : 131072   (zeroed KA, atomic KB, read KC)
// den    [8]           : 139264   (zeroed KA, atomic KB, read KC)
// wacc   [8][1024]     : 139280   (zeroed KA, atomic KC, read KD)
// hacc   [8][1024]     : 147472   (zeroed KA, atomic KD, read KD-epilogue)
// cnt    [1]           : 155664   (zeroed KA, ticket for KD last block)
#define UPART_OFF 0
#define NUM_OFF   131072
#define DEN_OFF   139264
#define WACC_OFF  139280
#define HACC_OFF  147472
#define CNT_OFF   155664
#define ZERO_BEG  131072
#define ZERO_CNT  24593    // num..cnt contiguous

// ---------------- reduction helpers ----------------
__device__ __forceinline__ float waveReduceSum(float v) {
#pragma unroll
    for (int k = 32; k >= 1; k >>= 1) v += __shfl_xor(v, k, 64);
    return v;
}
__device__ float blockReduceSum(float v) {
    __shared__ float sm[4];
    int lane = threadIdx.x & 63, wid = threadIdx.x >> 6;
    v = waveReduceSum(v);
    __syncthreads();
    if (lane == 0) sm[wid] = v;
    __syncthreads();
    return sm[0] + sm[1] + sm[2] + sm[3];
}

// ---------------- KA: u_part[g][b][d] = Wk[d, j in g] . (x0 Wq[:,g] + bq) ----
// grid 64 = (g=16 j-chunks of 64) x (h=4 d-chunks of 256). block 256.
// z-phase VECTORIZED: thread (jf = tid&15 float4-col, eg = tid>>4 e-group of
// 64) issues 64 independent float4 Wq loads. Also zeroes the atomic region.
__global__ void __launch_bounds__(256) kA(const float* __restrict__ x,
                                          const float* __restrict__ Wq,
                                          const float* __restrict__ bq,
                                          const float* __restrict__ Wk,
                                          float* __restrict__ ws) {
    const int tid = threadIdx.x;
    for (int zi = blockIdx.x * 256 + tid; zi < ZERO_CNT; zi += 16384)
        ws[ZERO_BEG + zi] = 0.f;
    const int gi = blockIdx.x >> 2, hi = blockIdx.x & 3;
    __shared__ float xs[8][1024];          // 32 KB
    __shared__ float4 zred4[16][8][16];    // 32 KB: (eg, b, jf)
    __shared__ float zf[8][64];            // 2 KB: finalized z (+bq)
    for (int jj = tid; jj < 2048; jj += 256) {   // 2048 float4 = 8 x 256
        int b = jj >> 8, off = jj & 255;
        ((float4*)xs[b])[off] = ((const float4*)(x + (size_t)b * S * D))[off];
    }
    __syncthreads();
    {   // z partials: 64 independent float4 loads per thread
        const int jf = tid & 15, eg = tid >> 4;
        const float4* wq4 = (const float4*)Wq + gi * 16 + jf;  // row stride 256
        const int e0 = eg * 64;
        float4 az[8];
#pragma unroll
        for (int b = 0; b < 8; ++b) az[b] = make_float4(0.f, 0.f, 0.f, 0.f);
#pragma unroll 8
        for (int e = 0; e < 64; ++e) {
            float4 w = wq4[(size_t)(e0 + e) * 256];
#pragma unroll
            for (int b = 0; b < 8; ++b) {
                float xv = xs[b][e0 + e];
                az[b].x += xv * w.x;
                az[b].y += xv * w.y;
                az[b].z += xv * w.z;
                az[b].w += xv * w.w;
            }
        }
#pragma unroll
        for (int b = 0; b < 8; ++b) zred4[eg][b][jf] = az[b];
    }
    __syncthreads();
    if (tid < 128) {   // reduce 16 e-groups -> zf (+bq)
        int b = tid >> 4, jf = tid & 15;
        float4 s = make_float4(0.f, 0.f, 0.f, 0.f);
#pragma unroll
        for (int g = 0; g < 16; ++g) {
            float4 v = zred4[g][b][jf];
            s.x += v.x; s.y += v.y; s.z += v.z; s.w += v.w;
        }
        float4 bb = ((const float4*)bq)[gi * 16 + jf];
        zf[b][jf * 4 + 0] = s.x + bb.x;
        zf[b][jf * 4 + 1] = s.y + bb.y;
        zf[b][jf * 4 + 2] = s.z + bb.z;
        zf[b][jf * 4 + 3] = s.w + bb.w;
    }
    __syncthreads();
    // u_part: thread owns d = hi*256 + tid; 16 independent float4 Wk loads
    {
        const int d = hi * 256 + tid;
        const float4* wk4 = (const float4*)(Wk + (size_t)d * D + gi * 64);
        float au[8] = {0.f, 0.f, 0.f, 0.f, 0.f, 0.f, 0.f, 0.f};
#pragma unroll
        for (int jq = 0; jq < 16; ++jq) {
            float4 w4 = wk4[jq];
#pragma unroll
            for (int b = 0; b < 8; ++b)
                au[b] += w4.x * zf[b][jq * 4 + 0] + w4.y * zf[b][jq * 4 + 1] +
                         w4.z * zf[b][jq * 4 + 2] + w4.w * zf[b][jq * 4 + 3];
        }
#pragma unroll
        for (int b = 0; b < 8; ++b)
            ws[UPART_OFF + (((size_t)gi * 8 + b) << 10) + d] = au[b];
    }
}

// ---------------- KB: scores + unstable softmax, atomic num/den --------------
// grid (256, 8) = 2048 blocks (8 blocks/CU -> full occupancy), block 256.
// Block: 8 t's of batch b. x read once (held in regs).
__global__ void __launch_bounds__(256) kB(const float* __restrict__ x,
                                          float* __restrict__ ws) {
    const int b = blockIdx.y;
    const int t0 = blockIdx.x * 8;
    const int tid = threadIdx.x;
    const int wave = tid >> 6, lane = tid & 63;
    const float4* xb4 = (const float4*)(x + (size_t)b * S * D);
    float4 xr[8];
#pragma unroll
    for (int t = 0; t < 8; ++t) xr[t] = xb4[(size_t)(t0 + t) * 256 + tid];
    // u[b, d-slice] = sum of 16 partials (L2-hot)
    float4 uv = {0.f, 0.f, 0.f, 0.f};
    const float4* up4 = (const float4*)(ws + UPART_OFF);
#pragma unroll
    for (int g = 0; g < 16; ++g) {
        float4 t = up4[(g * 8 + b) * 256 + tid];
        uv.x += t.x; uv.y += t.y; uv.z += t.z; uv.w += t.w;
    }
    __shared__ float part[8][256];
#pragma unroll
    for (int t = 0; t < 8; ++t)
        part[t][tid] = xr[t].x * uv.x + xr[t].y * uv.y + xr[t].z * uv.z + xr[t].w * uv.w;
    __syncthreads();
    __shared__ float s_sc[8];
#pragma unroll
    for (int r = 0; r < 2; ++r) {
        int t = wave * 2 + r;
        float v = part[t][lane] + part[t][lane + 64] + part[t][lane + 128] + part[t][lane + 192];
        v = waveReduceSum(v);
        if (lane == 0) s_sc[t] = v * 0.03125f;  // 1/sqrt(1024)
    }
    __syncthreads();
    // unstable softmax partials: scores ~ N(0,1) -> exp safe in fp32
    float p[8], l = 0.f;
#pragma unroll
    for (int t = 0; t < 8; ++t) {
        p[t] = __expf(s_sc[t]);
        l += p[t];
    }
    float4 wl = {0.f, 0.f, 0.f, 0.f};
#pragma unroll
    for (int t = 0; t < 8; ++t) {
        wl.x += p[t] * xr[t].x;
        wl.y += p[t] * xr[t].y;
        wl.z += p[t] * xr[t].z;
        wl.w += p[t] * xr[t].w;
    }
    float* nb = ws + NUM_OFF + b * 1024 + tid * 4;
    atomicAdd(nb + 0, wl.x);
    atomicAdd(nb + 1, wl.y);
    atomicAdd(nb + 2, wl.z);
    atomicAdd(nb + 3, wl.w);
    if (tid == 0) atomicAdd(ws + DEN_OFF + b, l);
}

// ---------------- KC: wacc += (num/den)[d-chunk] @ Wv[d-chunk, dp] -----------
// grid 128, block 256. d0=(bid>>2)*32 (K-chunk), dp=(bid&3)*256+tid.
__global__ void __launch_bounds__(256) kC(const float* __restrict__ Wv,
                                          float* __restrict__ ws) {
    const int tid = threadIdx.x;
    const int bid = blockIdx.x;
    const int d0 = (bid >> 2) * 32;
    const int dp = (bid & 3) * 256 + tid;
    __shared__ float invden[8], vs[8][32];
    if (tid < 8) invden[tid] = 1.f / ws[DEN_OFF + tid];
    __syncthreads();
    {
        int b = tid >> 5, dd = tid & 31;
        vs[b][dd] = ws[NUM_OFF + b * 1024 + d0 + dd] * invden[b];
    }
    __syncthreads();
    float acc[8] = {0.f, 0.f, 0.f, 0.f, 0.f, 0.f, 0.f, 0.f};
#pragma unroll 8
    for (int dd = 0; dd < 32; ++dd) {
        float wv = Wv[(size_t)(d0 + dd) * D + dp];
#pragma unroll
        for (int b = 0; b < 8; ++b) acc[b] += vs[b][dd] * wv;
    }
#pragma unroll
    for (int b = 0; b < 8; ++b)
        atomicAdd(ws + WACC_OFF + b * 1024 + dp, acc[b]);
}

// ---------------- KD: LN1 + Wd -> hacc atomics; LAST BLOCK runs classifier ---
// grid 128, block 256. Last-arriving block (device-scope ticket) executes the
// former kE: ReLU + LN2 + classifier for all 8 batches.
__global__ void __launch_bounds__(256) kD(const float* __restrict__ bv,
                                          const float* __restrict__ x,
                                          const float* __restrict__ g1,
                                          const float* __restrict__ b1,
                                          const float* __restrict__ Wd,
                                          const float* __restrict__ bd,
                                          const float* __restrict__ g2,
                                          const float* __restrict__ b2,
                                          const float* __restrict__ Wc,
                                          const float* __restrict__ bc,
                                          float* __restrict__ ws,
                                          float* __restrict__ out) {
    const int tid = threadIdx.x;
    const int bid = blockIdx.x;
    const int d0 = (bid >> 2) * 32;
    const int dp = (bid & 3) * 256 + tid;
    const int wave = tid >> 6, lane = tid & 63;
    __shared__ float sMu[8], sInv[8], vs[8][32];
    {
        const float4* wacc4 = (const float4*)(ws + WACC_OFF);
        const float4* bv4 = (const float4*)bv;
#pragma unroll
        for (int h = 0; h < 2; ++h) {
            int b = wave + h * 4;
            const float4* xb4r = (const float4*)(x + (size_t)b * S * D);
            float s = 0.f, ss = 0.f;
#pragma unroll
            for (int i = 0; i < 4; ++i) {
                int idx = lane + 64 * i;
                float4 wv = wacc4[b * 256 + idx];
                float4 bb = bv4[idx];
                float4 xv = xb4r[idx];
                float v0 = wv.x + bb.x + xv.x;
                float v1 = wv.y + bb.y + xv.y;
                float v2 = wv.z + bb.z + xv.z;
                float v3 = wv.w + bb.w + xv.w;
                s += v0 + v1 + v2 + v3;
                ss += v0 * v0 + v1 * v1 + v2 * v2 + v3 * v3;
            }
            s = waveReduceSum(s);
            ss = waveReduceSum(ss);
            if (lane == 0) {
                float mu = s * (1.0f / D);
                sMu[b] = mu;
                sInv[b] = rsqrtf(ss * (1.0f / D) - mu * mu + 1e-5f);
            }
        }
    }
    __syncthreads();
    {
        int b = tid >> 5, dd = tid & 31, d = d0 + dd;
        float v = ws[WACC_OFF + b * 1024 + d] + bv[d] + x[(size_t)b * S * D + d];
        vs[b][dd] = (v - sMu[b]) * sInv[b] * g1[d] + b1[d];
    }
    __syncthreads();
    float acc[8] = {0.f, 0.f, 0.f, 0.f, 0.f, 0.f, 0.f, 0.f};
#pragma unroll 8
    for (int dd = 0; dd < 32; ++dd) {
        float wv = Wd[(size_t)(d0 + dd) * D + dp];
#pragma unroll
        for (int b = 0; b < 8; ++b) acc[b] += vs[b][dd] * wv;
    }
#pragma unroll
    for (int b = 0; b < 8; ++b)
        atomicAdd(ws + HACC_OFF + b * 1024 + dp, acc[b]);

    // ---- last-block epilogue (former kE) ----
    __threadfence();                 // my hacc atomics device-visible
    __syncthreads();
    __shared__ unsigned ticket;
    if (tid == 0) ticket = atomicAdd((unsigned*)(ws + CNT_OFF), 1u);
    __syncthreads();
    if (ticket != 127u) return;
    __threadfence();                 // acquire: see all blocks' hacc/wacc
    for (int b = 0; b < 8; ++b) {
        const float mu1 = sMu[b], inv1 = sInv[b];
        float t[4];
        float s2 = 0.f, ss2 = 0.f;
#pragma unroll
        for (int i = 0; i < 4; ++i) {
            int e = tid * 4 + i;
            float v = ws[WACC_OFF + b * 1024 + e] + bv[e] + x[(size_t)b * S * D + e];
            float ln1v = (v - mu1) * inv1 * g1[e] + b1[e];
            float h = fmaxf(ws[HACC_OFF + b * 1024 + e] + bd[e], 0.f) + ln1v;
            t[i] = h;
            s2 += h;
            ss2 += h * h;
        }
        s2 = blockReduceSum(s2);
        ss2 = blockReduceSum(ss2);
        float mu2 = s2 * (1.0f / D);
        float inv2 = rsqrtf(ss2 * (1.0f / D) - mu2 * mu2 + 1e-5f);
        float p0 = 0.f, p1 = 0.f;
#pragma unroll
        for (int i = 0; i < 4; ++i) {
            int e = tid * 4 + i;
            float l2 = (t[i] - mu2) * inv2 * g2[e] + b2[e];
            p0 += l2 * Wc[e * 2 + 0];
            p1 += l2 * Wc[e * 2 + 1];
        }
        p0 = blockReduceSum(p0);
        p1 = blockReduceSum(p1);
        if (tid == 0) {
            out[b * 2 + 0] = p0 + bc[0];
            out[b * 2 + 1] = p1 + bc[1];
        }
        __syncthreads();
    }
}

extern "C" void kernel_launch(void* const* d_in, const int* in_sizes, int n_in,
                              void* d_out, int out_size, void* d_ws, size_t ws_size,
                              hipStream_t stream) {
    const float* x  = (const float*)d_in[0];
    const float* Wq = (const float*)d_in[1];
    const float* bq = (const float*)d_in[2];
    const float* Wk = (const float*)d_in[3];
    // bk (d_in[4]): constant over t -> cancels in softmax
    const float* Wv = (const float*)d_in[5];
    const float* bv = (const float*)d_in[6];
    const float* Wd = (const float*)d_in[7];
    const float* bd = (const float*)d_in[8];
    const float* g1 = (const float*)d_in[9];
    const float* b1 = (const float*)d_in[10];
    const float* g2 = (const float*)d_in[11];
    const float* b2 = (const float*)d_in[12];
    const float* Wc = (const float*)d_in[13];
    const float* bc = (const float*)d_in[14];
    float* out = (float*)d_out;
    float* ws = (float*)d_ws;

    // KA: merged Wq/Wk front-end -> u_part ; zeroes atomic accumulators
    kA<<<64, 256, 0, stream>>>(x, Wq, bq, Wk, ws);
    // KB: attention scores + unstable-softmax num/den atomics (full occupancy)
    kB<<<dim3(256, 8), 256, 0, stream>>>(x, ws);
    // KC: (num/den) @ Wv -> wacc atomics
    kC<<<128, 256, 0, stream>>>(Wv, ws);
    // KD: LN1 + Wd -> hacc atomics; last block runs ReLU+LN2+classifier
    kD<<<128, 256, 0, stream>>>(bv, x, g1, b1, Wd, bd, g2, b2, Wc, bc, ws, out);
}

// Round 9
// 212.081 us; speedup vs baseline: 1.0576x; 1.0576x over previous
//
#include <hip/hip_runtime.h>
#include <math.h>

#define B 8
#define S 2048
#define D 1024

// ---------------- workspace layout (floats) ----------------
// u_part [16][8][1024]   : 0       (written whole by KA, read by KB)
// num_p  [32][8][1024]   : 131072  (zeroed KA, atomic KB c=bx&31, read KC)
// den_p  [32][8]         : 393216  (zeroed KA, atomic KB, read KC)
// wacc_p [4][8][1024]    : 393472  (zeroed KA, atomic KC c=(bid>>2)&3, read KD)
// hacc_p [4][8][1024]    : 426240  (zeroed KA, atomic KD, read KD-epilogue)
// cnt    [1]             : 459008  (zeroed KA, ticket for KD last block)
#define UPART_OFF 0
#define NUMP_OFF  131072
#define DENP_OFF  393216
#define WACC_OFF  393472
#define HACC_OFF  426240
#define CNT_OFF   459008
#define ZERO_BEG  131072
#define ZERO_CNT  327937   // num_p..cnt contiguous

// ---------------- reduction helpers ----------------
__device__ __forceinline__ float waveReduceSum(float v) {
#pragma unroll
    for (int k = 32; k >= 1; k >>= 1) v += __shfl_xor(v, k, 64);
    return v;
}
__device__ float blockReduceSum(float v) {
    __shared__ float sm[4];
    int lane = threadIdx.x & 63, wid = threadIdx.x >> 6;
    v = waveReduceSum(v);
    __syncthreads();
    if (lane == 0) sm[wid] = v;
    __syncthreads();
    return sm[0] + sm[1] + sm[2] + sm[3];
}

// ---------------- KA: u_part[g][b][d] = Wk[d, j in g] . (x0 Wq[:,g] + bq) ----
// grid 64 = (g=16 j-chunks of 64) x (h=4 d-chunks of 256). block 256.
__global__ void __launch_bounds__(256) kA(const float* __restrict__ x,
                                          const float* __restrict__ Wq,
                                          const float* __restrict__ bq,
                                          const float* __restrict__ Wk,
                                          float* __restrict__ ws) {
    const int tid = threadIdx.x;
    for (int zi = blockIdx.x * 256 + tid; zi < ZERO_CNT; zi += 16384)
        ws[ZERO_BEG + zi] = 0.f;
    const int gi = blockIdx.x >> 2, hi = blockIdx.x & 3;
    __shared__ float xs[8][1024];          // 32 KB
    __shared__ float4 zred4[16][8][16];    // 32 KB: (eg, b, jf)
    __shared__ float zf[8][64];            // 2 KB: finalized z (+bq)
    for (int jj = tid; jj < 2048; jj += 256) {   // 2048 float4 = 8 x 256
        int b = jj >> 8, off = jj & 255;
        ((float4*)xs[b])[off] = ((const float4*)(x + (size_t)b * S * D))[off];
    }
    __syncthreads();
    {   // z partials: 64 independent float4 loads per thread
        const int jf = tid & 15, eg = tid >> 4;
        const float4* wq4 = (const float4*)Wq + gi * 16 + jf;  // row stride 256
        const int e0 = eg * 64;
        float4 az[8];
#pragma unroll
        for (int b = 0; b < 8; ++b) az[b] = make_float4(0.f, 0.f, 0.f, 0.f);
#pragma unroll 8
        for (int e = 0; e < 64; ++e) {
            float4 w = wq4[(size_t)(e0 + e) * 256];
#pragma unroll
            for (int b = 0; b < 8; ++b) {
                float xv = xs[b][e0 + e];
                az[b].x += xv * w.x;
                az[b].y += xv * w.y;
                az[b].z += xv * w.z;
                az[b].w += xv * w.w;
            }
        }
#pragma unroll
        for (int b = 0; b < 8; ++b) zred4[eg][b][jf] = az[b];
    }
    __syncthreads();
    if (tid < 128) {   // reduce 16 e-groups -> zf (+bq)
        int b = tid >> 4, jf = tid & 15;
        float4 s = make_float4(0.f, 0.f, 0.f, 0.f);
#pragma unroll
        for (int g = 0; g < 16; ++g) {
            float4 v = zred4[g][b][jf];
            s.x += v.x; s.y += v.y; s.z += v.z; s.w += v.w;
        }
        float4 bb = ((const float4*)bq)[gi * 16 + jf];
        zf[b][jf * 4 + 0] = s.x + bb.x;
        zf[b][jf * 4 + 1] = s.y + bb.y;
        zf[b][jf * 4 + 2] = s.z + bb.z;
        zf[b][jf * 4 + 3] = s.w + bb.w;
    }
    __syncthreads();
    // u_part: thread owns d = hi*256 + tid; 16 independent float4 Wk loads
    {
        const int d = hi * 256 + tid;
        const float4* wk4 = (const float4*)(Wk + (size_t)d * D + gi * 64);
        float au[8] = {0.f, 0.f, 0.f, 0.f, 0.f, 0.f, 0.f, 0.f};
#pragma unroll
        for (int jq = 0; jq < 16; ++jq) {
            float4 w4 = wk4[jq];
#pragma unroll
            for (int b = 0; b < 8; ++b)
                au[b] += w4.x * zf[b][jq * 4 + 0] + w4.y * zf[b][jq * 4 + 1] +
                         w4.z * zf[b][jq * 4 + 2] + w4.w * zf[b][jq * 4 + 3];
        }
#pragma unroll
        for (int b = 0; b < 8; ++b)
            ws[UPART_OFF + (((size_t)gi * 8 + b) << 10) + d] = au[b];
    }
}

// ---------------- KB: scores + unstable softmax -> PRIVATIZED num/den --------
// grid (256, 8), block 256. Block: 8 t's of batch b; atomic copy c = bx & 31
// (8 blocks/copy -> 8-deep chains instead of 256).
__global__ void __launch_bounds__(256) kB(const float* __restrict__ x,
                                          float* __restrict__ ws) {
    const int b = blockIdx.y;
    const int bx = blockIdx.x;
    const int t0 = bx * 8;
    const int c = bx & 31;
    const int tid = threadIdx.x;
    const int wave = tid >> 6, lane = tid & 63;
    const float4* xb4 = (const float4*)(x + (size_t)b * S * D);
    float4 xr[8];
#pragma unroll
    for (int t = 0; t < 8; ++t) xr[t] = xb4[(size_t)(t0 + t) * 256 + tid];
    // u[b, d-slice] = sum of 16 partials (L2/L3-hot)
    float4 uv = {0.f, 0.f, 0.f, 0.f};
    const float4* up4 = (const float4*)(ws + UPART_OFF);
#pragma unroll
    for (int g = 0; g < 16; ++g) {
        float4 t = up4[(g * 8 + b) * 256 + tid];
        uv.x += t.x; uv.y += t.y; uv.z += t.z; uv.w += t.w;
    }
    __shared__ float part[8][256];
#pragma unroll
    for (int t = 0; t < 8; ++t)
        part[t][tid] = xr[t].x * uv.x + xr[t].y * uv.y + xr[t].z * uv.z + xr[t].w * uv.w;
    __syncthreads();
    __shared__ float s_sc[8];
#pragma unroll
    for (int r = 0; r < 2; ++r) {
        int t = wave * 2 + r;
        float v = part[t][lane] + part[t][lane + 64] + part[t][lane + 128] + part[t][lane + 192];
        v = waveReduceSum(v);
        if (lane == 0) s_sc[t] = v * 0.03125f;  // 1/sqrt(1024)
    }
    __syncthreads();
    // unstable softmax partials: scores ~ N(0,1) -> exp safe in fp32
    float p[8], l = 0.f;
#pragma unroll
    for (int t = 0; t < 8; ++t) {
        p[t] = __expf(s_sc[t]);
        l += p[t];
    }
    float4 wl = {0.f, 0.f, 0.f, 0.f};
#pragma unroll
    for (int t = 0; t < 8; ++t) {
        wl.x += p[t] * xr[t].x;
        wl.y += p[t] * xr[t].y;
        wl.z += p[t] * xr[t].z;
        wl.w += p[t] * xr[t].w;
    }
    float* nb = ws + NUMP_OFF + (size_t)(c * 8 + b) * 1024 + tid * 4;
    atomicAdd(nb + 0, wl.x);
    atomicAdd(nb + 1, wl.y);
    atomicAdd(nb + 2, wl.z);
    atomicAdd(nb + 3, wl.w);
    if (tid == 0) atomicAdd(ws + DENP_OFF + c * 8 + b, l);
}

// ---------------- KC: wacc_p[c] += (num/den)[d-chunk] @ Wv[d-chunk, dp] ------
// grid 128, block 256. d0=(bid>>2)*32, dp=(bid&3)*256+tid, copy c=(bid>>2)&3.
__global__ void __launch_bounds__(256) kC(const float* __restrict__ Wv,
                                          float* __restrict__ ws) {
    const int tid = threadIdx.x;
    const int bid = blockIdx.x;
    const int d0 = (bid >> 2) * 32;
    const int dp = (bid & 3) * 256 + tid;
    const int c = (bid >> 2) & 3;
    __shared__ float dsm[256], invden[8], vs[8][32];
    dsm[tid] = ws[DENP_OFF + tid];   // den_p is exactly 256 floats (c*8+b)
    __syncthreads();
    if (tid < 8) {
        float s = 0.f;
#pragma unroll
        for (int cc = 0; cc < 32; ++cc) s += dsm[cc * 8 + tid];
        invden[tid] = 1.f / s;
    }
    __syncthreads();
    {   // vs[b][dd] = (sum of 32 num copies) / den
        int b = tid >> 5, dd = tid & 31;
        float s = 0.f;
#pragma unroll 8
        for (int cc = 0; cc < 32; ++cc)
            s += ws[NUMP_OFF + (size_t)(cc * 8 + b) * 1024 + d0 + dd];
        vs[b][dd] = s * invden[b];
    }
    __syncthreads();
    float acc[8] = {0.f, 0.f, 0.f, 0.f, 0.f, 0.f, 0.f, 0.f};
#pragma unroll 8
    for (int dd = 0; dd < 32; ++dd) {
        float wv = Wv[(size_t)(d0 + dd) * D + dp];
#pragma unroll
        for (int b = 0; b < 8; ++b) acc[b] += vs[b][dd] * wv;
    }
#pragma unroll
    for (int b = 0; b < 8; ++b)
        atomicAdd(ws + WACC_OFF + (size_t)c * 8192 + b * 1024 + dp, acc[b]);
}

// ---------------- KD: LN1 + Wd -> hacc_p atomics; LAST BLOCK: classifier -----
// grid 128, block 256. wacc = sum of 4 copies; hacc copy c2=(bid>>2)&3.
__global__ void __launch_bounds__(256) kD(const float* __restrict__ bv,
                                          const float* __restrict__ x,
                                          const float* __restrict__ g1,
                                          const float* __restrict__ b1,
                                          const float* __restrict__ Wd,
                                          const float* __restrict__ bd,
                                          const float* __restrict__ g2,
                                          const float* __restrict__ b2,
                                          const float* __restrict__ Wc,
                                          const float* __restrict__ bc,
                                          float* __restrict__ ws,
                                          float* __restrict__ out) {
    const int tid = threadIdx.x;
    const int bid = blockIdx.x;
    const int d0 = (bid >> 2) * 32;
    const int dp = (bid & 3) * 256 + tid;
    const int c2 = (bid >> 2) & 3;
    const int wave = tid >> 6, lane = tid & 63;
    __shared__ float sMu[8], sInv[8], vs[8][32];
    {
        const float4* wacc4 = (const float4*)(ws + WACC_OFF);  // 4 x 2048 f4
        const float4* bv4 = (const float4*)bv;
#pragma unroll
        for (int h = 0; h < 2; ++h) {
            int b = wave + h * 4;
            const float4* xb4r = (const float4*)(x + (size_t)b * S * D);
            float s = 0.f, ss = 0.f;
#pragma unroll
            for (int i = 0; i < 4; ++i) {
                int idx = lane + 64 * i;
                float4 wv = wacc4[0 * 2048 + b * 256 + idx];
                float4 w1 = wacc4[1 * 2048 + b * 256 + idx];
                float4 w2 = wacc4[2 * 2048 + b * 256 + idx];
                float4 w3 = wacc4[3 * 2048 + b * 256 + idx];
                float4 bb = bv4[idx];
                float4 xv = xb4r[idx];
                float v0 = wv.x + w1.x + w2.x + w3.x + bb.x + xv.x;
                float v1 = wv.y + w1.y + w2.y + w3.y + bb.y + xv.y;
                float v2 = wv.z + w1.z + w2.z + w3.z + bb.z + xv.z;
                float v3 = wv.w + w1.w + w2.w + w3.w + bb.w + xv.w;
                s += v0 + v1 + v2 + v3;
                ss += v0 * v0 + v1 * v1 + v2 * v2 + v3 * v3;
            }
            s = waveReduceSum(s);
            ss = waveReduceSum(ss);
            if (lane == 0) {
                float mu = s * (1.0f / D);
                sMu[b] = mu;
                sInv[b] = rsqrtf(ss * (1.0f / D) - mu * mu + 1e-5f);
            }
        }
    }
    __syncthreads();
    {
        int b = tid >> 5, dd = tid & 31, d = d0 + dd;
        float v = ws[WACC_OFF + 0 * 8192 + b * 1024 + d] +
                  ws[WACC_OFF + 1 * 8192 + b * 1024 + d] +
                  ws[WACC_OFF + 2 * 8192 + b * 1024 + d] +
                  ws[WACC_OFF + 3 * 8192 + b * 1024 + d] +
                  bv[d] + x[(size_t)b * S * D + d];
        vs[b][dd] = (v - sMu[b]) * sInv[b] * g1[d] + b1[d];
    }
    __syncthreads();
    float acc[8] = {0.f, 0.f, 0.f, 0.f, 0.f, 0.f, 0.f, 0.f};
#pragma unroll 8
    for (int dd = 0; dd < 32; ++dd) {
        float wv = Wd[(size_t)(d0 + dd) * D + dp];
#pragma unroll
        for (int b = 0; b < 8; ++b) acc[b] += vs[b][dd] * wv;
    }
#pragma unroll
    for (int b = 0; b < 8; ++b)
        atomicAdd(ws + HACC_OFF + (size_t)c2 * 8192 + b * 1024 + dp, acc[b]);

    // ---- last-block epilogue (classifier) ----
    __threadfence();                 // my hacc atomics device-visible
    __syncthreads();
    __shared__ unsigned ticket;
    if (tid == 0) ticket = atomicAdd((unsigned*)(ws + CNT_OFF), 1u);
    __syncthreads();
    if (ticket != 127u) return;
    __threadfence();                 // acquire: see all blocks' hacc/wacc
    for (int b = 0; b < 8; ++b) {
        const float mu1 = sMu[b], inv1 = sInv[b];
        float t[4];
        float s2 = 0.f, ss2 = 0.f;
#pragma unroll
        for (int i = 0; i < 4; ++i) {
            int e = tid * 4 + i;
            float v = ws[WACC_OFF + 0 * 8192 + b * 1024 + e] +
                      ws[WACC_OFF + 1 * 8192 + b * 1024 + e] +
                      ws[WACC_OFF + 2 * 8192 + b * 1024 + e] +
                      ws[WACC_OFF + 3 * 8192 + b * 1024 + e] +
                      bv[e] + x[(size_t)b * S * D + e];
            float ln1v = (v - mu1) * inv1 * g1[e] + b1[e];
            float hv = ws[HACC_OFF + 0 * 8192 + b * 1024 + e] +
                       ws[HACC_OFF + 1 * 8192 + b * 1024 + e] +
                       ws[HACC_OFF + 2 * 8192 + b * 1024 + e] +
                       ws[HACC_OFF + 3 * 8192 + b * 1024 + e];
            float h = fmaxf(hv + bd[e], 0.f) + ln1v;
            t[i] = h;
            s2 += h;
            ss2 += h * h;
        }
        s2 = blockReduceSum(s2);
        ss2 = blockReduceSum(ss2);
        float mu2 = s2 * (1.0f / D);
        float inv2 = rsqrtf(ss2 * (1.0f / D) - mu2 * mu2 + 1e-5f);
        float p0 = 0.f, p1 = 0.f;
#pragma unroll
        for (int i = 0; i < 4; ++i) {
            int e = tid * 4 + i;
            float l2 = (t[i] - mu2) * inv2 * g2[e] + b2[e];
            p0 += l2 * Wc[e * 2 + 0];
            p1 += l2 * Wc[e * 2 + 1];
        }
        p0 = blockReduceSum(p0);
        p1 = blockReduceSum(p1);
        if (tid == 0) {
            out[b * 2 + 0] = p0 + bc[0];
            out[b * 2 + 1] = p1 + bc[1];
        }
        __syncthreads();
    }
}

extern "C" void kernel_launch(void* const* d_in, const int* in_sizes, int n_in,
                              void* d_out, int out_size, void* d_ws, size_t ws_size,
                              hipStream_t stream) {
    const float* x  = (const float*)d_in[0];
    const float* Wq = (const float*)d_in[1];
    const float* bq = (const float*)d_in[2];
    const float* Wk = (const float*)d_in[3];
    // bk (d_in[4]): constant over t -> cancels in softmax
    const float* Wv = (const float*)d_in[5];
    const float* bv = (const float*)d_in[6];
    const float* Wd = (const float*)d_in[7];
    const float* bd = (const float*)d_in[8];
    const float* g1 = (const float*)d_in[9];
    const float* b1 = (const float*)d_in[10];
    const float* g2 = (const float*)d_in[11];
    const float* b2 = (const float*)d_in[12];
    const float* Wc = (const float*)d_in[13];
    const float* bc = (const float*)d_in[14];
    float* out = (float*)d_out;
    float* ws = (float*)d_ws;

    // KA: merged Wq/Wk front-end -> u_part ; zeroes all atomic accumulators
    kA<<<64, 256, 0, stream>>>(x, Wq, bq, Wk, ws);
    // KB: scores + unstable softmax -> 32-way privatized num/den
    kB<<<dim3(256, 8), 256, 0, stream>>>(x, ws);
    // KC: combine + @Wv -> 4-way privatized wacc
    kC<<<128, 256, 0, stream>>>(Wv, ws);
    // KD: LN1 + @Wd -> 4-way privatized hacc; last block: classifier
    kD<<<128, 256, 0, stream>>>(bv, x, g1, b1, Wd, bd, g2, b2, Wc, bc, ws, out);
}

// Round 10
// 181.119 us; speedup vs baseline: 1.2384x; 1.1709x over previous
//
#include <hip/hip_runtime.h>
#include <math.h>

#define B 8
#define S 2048
#define D 1024

// ---------------- workspace layout (floats) ----------------
// u_part   [16][8][1024]  : 0        (written whole by KA, read by KB)
// num_part [128][8][1024] : 131072   (written whole by KB, read by KC)
// den_part [128][8]       : 1179648  (written whole by KB, read by KC)
// wacc_p   [4][8][1024]   : 1180672  (zeroed KA, atomic KC, read KD)
// hacc_p   [4][8][1024]   : 1213440  (zeroed KA, atomic KD, read epilogue)
// cnt      [1]            : 1246208  (zeroed KA, ticket for KD last block)
#define UPART_OFF 0
#define NUMP_OFF  131072
#define DENP_OFF  1179648
#define WACC_OFF  1180672
#define HACC_OFF  1213440
#define CNT_OFF   1246208
#define ZERO_BEG  1180672
#define ZERO_CNT  65537    // wacc_p..cnt contiguous

// ---------------- reduction helpers ----------------
__device__ __forceinline__ float waveReduceSum(float v) {
#pragma unroll
    for (int k = 32; k >= 1; k >>= 1) v += __shfl_xor(v, k, 64);
    return v;
}
__device__ float blockReduceSum(float v) {
    __shared__ float sm[4];
    int lane = threadIdx.x & 63, wid = threadIdx.x >> 6;
    v = waveReduceSum(v);
    __syncthreads();
    if (lane == 0) sm[wid] = v;
    __syncthreads();
    return sm[0] + sm[1] + sm[2] + sm[3];
}

// ---------------- KA: u_part[g][b][d] = Wk[d, j in g] . (x0 Wq[:,g] + bq) ----
// grid 64 = (g=16 j-chunks of 64) x (h=4 d-chunks of 256). block 256.
__global__ void __launch_bounds__(256) kA(const float* __restrict__ x,
                                          const float* __restrict__ Wq,
                                          const float* __restrict__ bq,
                                          const float* __restrict__ Wk,
                                          float* __restrict__ ws) {
    const int tid = threadIdx.x;
    for (int zi = blockIdx.x * 256 + tid; zi < ZERO_CNT; zi += 16384)
        ws[ZERO_BEG + zi] = 0.f;
    const int gi = blockIdx.x >> 2, hi = blockIdx.x & 3;
    __shared__ float xs[8][1024];          // 32 KB
    __shared__ float4 zred4[16][8][16];    // 32 KB: (eg, b, jf)
    __shared__ float zf[8][64];            // 2 KB: finalized z (+bq)
    for (int jj = tid; jj < 2048; jj += 256) {   // 2048 float4 = 8 x 256
        int b = jj >> 8, off = jj & 255;
        ((float4*)xs[b])[off] = ((const float4*)(x + (size_t)b * S * D))[off];
    }
    __syncthreads();
    {   // z partials: 64 independent float4 loads per thread
        const int jf = tid & 15, eg = tid >> 4;
        const float4* wq4 = (const float4*)Wq + gi * 16 + jf;  // row stride 256
        const int e0 = eg * 64;
        float4 az[8];
#pragma unroll
        for (int b = 0; b < 8; ++b) az[b] = make_float4(0.f, 0.f, 0.f, 0.f);
#pragma unroll 8
        for (int e = 0; e < 64; ++e) {
            float4 w = wq4[(size_t)(e0 + e) * 256];
#pragma unroll
            for (int b = 0; b < 8; ++b) {
                float xv = xs[b][e0 + e];
                az[b].x += xv * w.x;
                az[b].y += xv * w.y;
                az[b].z += xv * w.z;
                az[b].w += xv * w.w;
            }
        }
#pragma unroll
        for (int b = 0; b < 8; ++b) zred4[eg][b][jf] = az[b];
    }
    __syncthreads();
    if (tid < 128) {   // reduce 16 e-groups -> zf (+bq)
        int b = tid >> 4, jf = tid & 15;
        float4 s = make_float4(0.f, 0.f, 0.f, 0.f);
#pragma unroll
        for (int g = 0; g < 16; ++g) {
            float4 v = zred4[g][b][jf];
            s.x += v.x; s.y += v.y; s.z += v.z; s.w += v.w;
        }
        float4 bb = ((const float4*)bq)[gi * 16 + jf];
        zf[b][jf * 4 + 0] = s.x + bb.x;
        zf[b][jf * 4 + 1] = s.y + bb.y;
        zf[b][jf * 4 + 2] = s.z + bb.z;
        zf[b][jf * 4 + 3] = s.w + bb.w;
    }
    __syncthreads();
    // u_part: thread owns d = hi*256 + tid; 16 independent float4 Wk loads
    {
        const int d = hi * 256 + tid;
        const float4* wk4 = (const float4*)(Wk + (size_t)d * D + gi * 64);
        float au[8] = {0.f, 0.f, 0.f, 0.f, 0.f, 0.f, 0.f, 0.f};
#pragma unroll
        for (int jq = 0; jq < 16; ++jq) {
            float4 w4 = wk4[jq];
#pragma unroll
            for (int b = 0; b < 8; ++b)
                au[b] += w4.x * zf[b][jq * 4 + 0] + w4.y * zf[b][jq * 4 + 1] +
                         w4.z * zf[b][jq * 4 + 2] + w4.w * zf[b][jq * 4 + 3];
        }
#pragma unroll
        for (int b = 0; b < 8; ++b)
            ws[UPART_OFF + (((size_t)gi * 8 + b) << 10) + d] = au[b];
    }
}

// ---------------- KB: scores + unstable softmax -> NON-ATOMIC partials -------
// grid (128, 8), block 256. Block: 16 t's of batch b; exclusively owns
// num_part[bx][b][*] and den_part[bx][b] -> plain stores, zero atomics.
__global__ void __launch_bounds__(256) kB(const float* __restrict__ x,
                                          float* __restrict__ ws) {
    const int b = blockIdx.y;
    const int bx = blockIdx.x;
    const int t0 = bx * 16;
    const int tid = threadIdx.x;
    const int wave = tid >> 6, lane = tid & 63;
    const float4* xb4 = (const float4*)(x + (size_t)b * S * D);
    float4 xr[16];
#pragma unroll
    for (int t = 0; t < 16; ++t) xr[t] = xb4[(size_t)(t0 + t) * 256 + tid];
    // u[b, d-slice] = sum of 16 u_part slices (L2/L3-hot)
    float4 uv = {0.f, 0.f, 0.f, 0.f};
    const float4* up4 = (const float4*)(ws + UPART_OFF);
#pragma unroll
    for (int g = 0; g < 16; ++g) {
        float4 t = up4[(g * 8 + b) * 256 + tid];
        uv.x += t.x; uv.y += t.y; uv.z += t.z; uv.w += t.w;
    }
    __shared__ float part[16][256];
#pragma unroll
    for (int t = 0; t < 16; ++t)
        part[t][tid] = xr[t].x * uv.x + xr[t].y * uv.y + xr[t].z * uv.z + xr[t].w * uv.w;
    __syncthreads();
    __shared__ float s_sc[16];
#pragma unroll
    for (int r = 0; r < 4; ++r) {
        int t = wave * 4 + r;
        float v = part[t][lane] + part[t][lane + 64] + part[t][lane + 128] + part[t][lane + 192];
        v = waveReduceSum(v);
        if (lane == 0) s_sc[t] = v * 0.03125f;  // 1/sqrt(1024)
    }
    __syncthreads();
    // unstable softmax partials: scores ~ N(0,1) -> exp safe in fp32
    float p[16], l = 0.f;
#pragma unroll
    for (int t = 0; t < 16; ++t) {
        p[t] = __expf(s_sc[t]);
        l += p[t];
    }
    float4 wl = {0.f, 0.f, 0.f, 0.f};
#pragma unroll
    for (int t = 0; t < 16; ++t) {
        wl.x += p[t] * xr[t].x;
        wl.y += p[t] * xr[t].y;
        wl.z += p[t] * xr[t].z;
        wl.w += p[t] * xr[t].w;
    }
    ((float4*)(ws + NUMP_OFF + (size_t)(bx * 8 + b) * 1024))[tid] = wl;
    if (tid == 0) ws[DENP_OFF + bx * 8 + b] = l;
}

// ---------------- KC: sum 128 partials -> (num/den) @ Wv -> wacc_p atomics ---
// grid 128, block 256. d0=(bid>>2)*32, dp=(bid&3)*256+tid, copy c=(bid>>2)&3.
__global__ void __launch_bounds__(256) kC(const float* __restrict__ Wv,
                                          float* __restrict__ ws) {
    const int tid = threadIdx.x;
    const int bid = blockIdx.x;
    const int d0 = (bid >> 2) * 32;
    const int dp = (bid & 3) * 256 + tid;
    const int c = (bid >> 2) & 3;
    __shared__ float dsm[1024], invden[8], vs[8][32];
    for (int j = tid; j < 1024; j += 256) dsm[j] = ws[DENP_OFF + j];
    __syncthreads();
    if (tid < 8) {
        float s = 0.f;
        for (int pp = 0; pp < 128; ++pp) s += dsm[pp * 8 + tid];
        invden[tid] = 1.f / s;
    }
    __syncthreads();
    {   // vs[b][dd] = (sum of 128 num partials) / den
        int b = tid >> 5, dd = tid & 31;
        float s = 0.f;
#pragma unroll 16
        for (int pp = 0; pp < 128; ++pp)
            s += ws[NUMP_OFF + (size_t)(pp * 8 + b) * 1024 + d0 + dd];
        vs[b][dd] = s * invden[b];
    }
    __syncthreads();
    float acc[8] = {0.f, 0.f, 0.f, 0.f, 0.f, 0.f, 0.f, 0.f};
#pragma unroll 8
    for (int dd = 0; dd < 32; ++dd) {
        float wv = Wv[(size_t)(d0 + dd) * D + dp];
#pragma unroll
        for (int b = 0; b < 8; ++b) acc[b] += vs[b][dd] * wv;
    }
#pragma unroll
    for (int b = 0; b < 8; ++b)
        atomicAdd(ws + WACC_OFF + (size_t)c * 8192 + b * 1024 + dp, acc[b]);
}

// ---------------- KD: LN1 + Wd -> hacc_p atomics; LAST BLOCK: classifier -----
// grid 128, block 256. wacc = sum of 4 copies; hacc copy c2=(bid>>2)&3.
__global__ void __launch_bounds__(256) kD(const float* __restrict__ bv,
                                          const float* __restrict__ x,
                                          const float* __restrict__ g1,
                                          const float* __restrict__ b1,
                                          const float* __restrict__ Wd,
                                          const float* __restrict__ bd,
                                          const float* __restrict__ g2,
                                          const float* __restrict__ b2,
                                          const float* __restrict__ Wc,
                                          const float* __restrict__ bc,
                                          float* __restrict__ ws,
                                          float* __restrict__ out) {
    const int tid = threadIdx.x;
    const int bid = blockIdx.x;
    const int d0 = (bid >> 2) * 32;
    const int dp = (bid & 3) * 256 + tid;
    const int c2 = (bid >> 2) & 3;
    const int wave = tid >> 6, lane = tid & 63;
    __shared__ float sMu[8], sInv[8], vs[8][32];
    {
        const float4* wacc4 = (const float4*)(ws + WACC_OFF);  // 4 x 2048 f4
        const float4* bv4 = (const float4*)bv;
#pragma unroll
        for (int h = 0; h < 2; ++h) {
            int b = wave + h * 4;
            const float4* xb4r = (const float4*)(x + (size_t)b * S * D);
            float s = 0.f, ss = 0.f;
#pragma unroll
            for (int i = 0; i < 4; ++i) {
                int idx = lane + 64 * i;
                float4 wv = wacc4[0 * 2048 + b * 256 + idx];
                float4 w1 = wacc4[1 * 2048 + b * 256 + idx];
                float4 w2 = wacc4[2 * 2048 + b * 256 + idx];
                float4 w3 = wacc4[3 * 2048 + b * 256 + idx];
                float4 bb = bv4[idx];
                float4 xv = xb4r[idx];
                float v0 = wv.x + w1.x + w2.x + w3.x + bb.x + xv.x;
                float v1 = wv.y + w1.y + w2.y + w3.y + bb.y + xv.y;
                float v2 = wv.z + w1.z + w2.z + w3.z + bb.z + xv.z;
                float v3 = wv.w + w1.w + w2.w + w3.w + bb.w + xv.w;
                s += v0 + v1 + v2 + v3;
                ss += v0 * v0 + v1 * v1 + v2 * v2 + v3 * v3;
            }
            s = waveReduceSum(s);
            ss = waveReduceSum(ss);
            if (lane == 0) {
                float mu = s * (1.0f / D);
                sMu[b] = mu;
                sInv[b] = rsqrtf(ss * (1.0f / D) - mu * mu + 1e-5f);
            }
        }
    }
    __syncthreads();
    {
        int b = tid >> 5, dd = tid & 31, d = d0 + dd;
        float v = ws[WACC_OFF + 0 * 8192 + b * 1024 + d] +
                  ws[WACC_OFF + 1 * 8192 + b * 1024 + d] +
                  ws[WACC_OFF + 2 * 8192 + b * 1024 + d] +
                  ws[WACC_OFF + 3 * 8192 + b * 1024 + d] +
                  bv[d] + x[(size_t)b * S * D + d];
        vs[b][dd] = (v - sMu[b]) * sInv[b] * g1[d] + b1[d];
    }
    __syncthreads();
    float acc[8] = {0.f, 0.f, 0.f, 0.f, 0.f, 0.f, 0.f, 0.f};
#pragma unroll 8
    for (int dd = 0; dd < 32; ++dd) {
        float wv = Wd[(size_t)(d0 + dd) * D + dp];
#pragma unroll
        for (int b = 0; b < 8; ++b) acc[b] += vs[b][dd] * wv;
    }
#pragma unroll
    for (int b = 0; b < 8; ++b)
        atomicAdd(ws + HACC_OFF + (size_t)c2 * 8192 + b * 1024 + dp, acc[b]);

    // ---- last-block epilogue (classifier) ----
    __threadfence();                 // my hacc atomics device-visible
    __syncthreads();
    __shared__ unsigned ticket;
    if (tid == 0) ticket = atomicAdd((unsigned*)(ws + CNT_OFF), 1u);
    __syncthreads();
    if (ticket != 127u) return;
    __threadfence();                 // acquire: see all blocks' hacc/wacc
    for (int b = 0; b < 8; ++b) {
        const float mu1 = sMu[b], inv1 = sInv[b];
        float t[4];
        float s2 = 0.f, ss2 = 0.f;
#pragma unroll
        for (int i = 0; i < 4; ++i) {
            int e = tid * 4 + i;
            float v = ws[WACC_OFF + 0 * 8192 + b * 1024 + e] +
                      ws[WACC_OFF + 1 * 8192 + b * 1024 + e] +
                      ws[WACC_OFF + 2 * 8192 + b * 1024 + e] +
                      ws[WACC_OFF + 3 * 8192 + b * 1024 + e] +
                      bv[e] + x[(size_t)b * S * D + e];
            float ln1v = (v - mu1) * inv1 * g1[e] + b1[e];
            float hv = ws[HACC_OFF + 0 * 8192 + b * 1024 + e] +
                       ws[HACC_OFF + 1 * 8192 + b * 1024 + e] +
                       ws[HACC_OFF + 2 * 8192 + b * 1024 + e] +
                       ws[HACC_OFF + 3 * 8192 + b * 1024 + e];
            float h = fmaxf(hv + bd[e], 0.f) + ln1v;
            t[i] = h;
            s2 += h;
            ss2 += h * h;
        }
        s2 = blockReduceSum(s2);
        ss2 = blockReduceSum(ss2);
        float mu2 = s2 * (1.0f / D);
        float inv2 = rsqrtf(ss2 * (1.0f / D) - mu2 * mu2 + 1e-5f);
        float p0 = 0.f, p1 = 0.f;
#pragma unroll
        for (int i = 0; i < 4; ++i) {
            int e = tid * 4 + i;
            float l2 = (t[i] - mu2) * inv2 * g2[e] + b2[e];
            p0 += l2 * Wc[e * 2 + 0];
            p1 += l2 * Wc[e * 2 + 1];
        }
        p0 = blockReduceSum(p0);
        p1 = blockReduceSum(p1);
        if (tid == 0) {
            out[b * 2 + 0] = p0 + bc[0];
            out[b * 2 + 1] = p1 + bc[1];
        }
        __syncthreads();
    }
}

extern "C" void kernel_launch(void* const* d_in, const int* in_sizes, int n_in,
                              void* d_out, int out_size, void* d_ws, size_t ws_size,
                              hipStream_t stream) {
    const float* x  = (const float*)d_in[0];
    const float* Wq = (const float*)d_in[1];
    const float* bq = (const float*)d_in[2];
    const float* Wk = (const float*)d_in[3];
    // bk (d_in[4]): constant over t -> cancels in softmax
    const float* Wv = (const float*)d_in[5];
    const float* bv = (const float*)d_in[6];
    const float* Wd = (const float*)d_in[7];
    const float* bd = (const float*)d_in[8];
    const float* g1 = (const float*)d_in[9];
    const float* b1 = (const float*)d_in[10];
    const float* g2 = (const float*)d_in[11];
    const float* b2 = (const float*)d_in[12];
    const float* Wc = (const float*)d_in[13];
    const float* bc = (const float*)d_in[14];
    float* out = (float*)d_out;
    float* ws = (float*)d_ws;

    // KA: merged Wq/Wk front-end -> u_part ; zeroes wacc/hacc/cnt
    kA<<<64, 256, 0, stream>>>(x, Wq, bq, Wk, ws);
    // KB: scores + unstable softmax -> NON-ATOMIC num/den partials
    kB<<<dim3(128, 8), 256, 0, stream>>>(x, ws);
    // KC: reduce 128 partials + @Wv -> 4-way privatized wacc
    kC<<<128, 256, 0, stream>>>(Wv, ws);
    // KD: LN1 + @Wd -> 4-way privatized hacc; last block: classifier
    kD<<<128, 256, 0, stream>>>(bv, x, g1, b1, Wd, bd, g2, b2, Wc, bc, ws, out);
}

// Round 11
// 163.792 us; speedup vs baseline: 1.3694x; 1.1058x over previous
//
#include <hip/hip_runtime.h>
#include <math.h>

#define B 8
#define S 2048
#define D 1024

// ---------------- workspace layout (floats) ----------------
// u_part   [16][8][1024]  : 0        (written whole by KA, read by KB)
// num_part [128][8][1024] : 131072   (written whole by KB, read by KC)
// den_part [128][8]       : 1179648  (written whole by KB, read by KC)
// wacc_p   [4][8][1024]   : 1180672  (zeroed KA, atomic KC, read KD/KE)
// hacc_p   [4][8][1024]   : 1213440  (zeroed KA, atomic KD, read KE)
#define UPART_OFF 0
#define NUMP_OFF  131072
#define DENP_OFF  1179648
#define WACC_OFF  1180672
#define HACC_OFF  1213440
#define ZERO_BEG  1180672
#define ZERO_CNT  65536    // wacc_p + hacc_p contiguous

// ---------------- reduction helpers ----------------
__device__ __forceinline__ float waveReduceSum(float v) {
#pragma unroll
    for (int k = 32; k >= 1; k >>= 1) v += __shfl_xor(v, k, 64);
    return v;
}
__device__ float blockReduceSum(float v) {
    __shared__ float sm[4];
    int lane = threadIdx.x & 63, wid = threadIdx.x >> 6;
    v = waveReduceSum(v);
    __syncthreads();
    if (lane == 0) sm[wid] = v;
    __syncthreads();
    return sm[0] + sm[1] + sm[2] + sm[3];
}

// ---------------- KA: u_part[g][b][d] = Wk[d, j in g] . (x0 Wq[:,g] + bq) ----
// grid 64 = (g=16 j-chunks of 64) x (h=4 d-chunks of 256). block 256.
__global__ void __launch_bounds__(256) kA(const float* __restrict__ x,
                                          const float* __restrict__ Wq,
                                          const float* __restrict__ bq,
                                          const float* __restrict__ Wk,
                                          float* __restrict__ ws) {
    const int tid = threadIdx.x;
    for (int zi = blockIdx.x * 256 + tid; zi < ZERO_CNT; zi += 16384)
        ws[ZERO_BEG + zi] = 0.f;
    const int gi = blockIdx.x >> 2, hi = blockIdx.x & 3;
    __shared__ float xs[8][1024];          // 32 KB
    __shared__ float4 zred4[16][8][16];    // 32 KB: (eg, b, jf)
    __shared__ float zf[8][64];            // 2 KB: finalized z (+bq)
    for (int jj = tid; jj < 2048; jj += 256) {   // 2048 float4 = 8 x 256
        int b = jj >> 8, off = jj & 255;
        ((float4*)xs[b])[off] = ((const float4*)(x + (size_t)b * S * D))[off];
    }
    __syncthreads();
    {   // z partials: 64 independent float4 loads per thread
        const int jf = tid & 15, eg = tid >> 4;
        const float4* wq4 = (const float4*)Wq + gi * 16 + jf;  // row stride 256
        const int e0 = eg * 64;
        float4 az[8];
#pragma unroll
        for (int b = 0; b < 8; ++b) az[b] = make_float4(0.f, 0.f, 0.f, 0.f);
#pragma unroll 8
        for (int e = 0; e < 64; ++e) {
            float4 w = wq4[(size_t)(e0 + e) * 256];
#pragma unroll
            for (int b = 0; b < 8; ++b) {
                float xv = xs[b][e0 + e];
                az[b].x += xv * w.x;
                az[b].y += xv * w.y;
                az[b].z += xv * w.z;
                az[b].w += xv * w.w;
            }
        }
#pragma unroll
        for (int b = 0; b < 8; ++b) zred4[eg][b][jf] = az[b];
    }
    __syncthreads();
    if (tid < 128) {   // reduce 16 e-groups -> zf (+bq)
        int b = tid >> 4, jf = tid & 15;
        float4 s = make_float4(0.f, 0.f, 0.f, 0.f);
#pragma unroll
        for (int g = 0; g < 16; ++g) {
            float4 v = zred4[g][b][jf];
            s.x += v.x; s.y += v.y; s.z += v.z; s.w += v.w;
        }
        float4 bb = ((const float4*)bq)[gi * 16 + jf];
        zf[b][jf * 4 + 0] = s.x + bb.x;
        zf[b][jf * 4 + 1] = s.y + bb.y;
        zf[b][jf * 4 + 2] = s.z + bb.z;
        zf[b][jf * 4 + 3] = s.w + bb.w;
    }
    __syncthreads();
    // u_part: thread owns d = hi*256 + tid; 16 independent float4 Wk loads
    {
        const int d = hi * 256 + tid;
        const float4* wk4 = (const float4*)(Wk + (size_t)d * D + gi * 64);
        float au[8] = {0.f, 0.f, 0.f, 0.f, 0.f, 0.f, 0.f, 0.f};
#pragma unroll
        for (int jq = 0; jq < 16; ++jq) {
            float4 w4 = wk4[jq];
#pragma unroll
            for (int b = 0; b < 8; ++b)
                au[b] += w4.x * zf[b][jq * 4 + 0] + w4.y * zf[b][jq * 4 + 1] +
                         w4.z * zf[b][jq * 4 + 2] + w4.w * zf[b][jq * 4 + 3];
        }
#pragma unroll
        for (int b = 0; b < 8; ++b)
            ws[UPART_OFF + (((size_t)gi * 8 + b) << 10) + d] = au[b];
    }
}

// ---------------- KB: scores + unstable softmax -> NON-ATOMIC partials -------
// grid (128, 8), block 256. Block: 16 t's of batch b; exclusively owns
// num_part[bx][b][*] and den_part[bx][b] -> plain stores, zero atomics.
__global__ void __launch_bounds__(256) kB(const float* __restrict__ x,
                                          float* __restrict__ ws) {
    const int b = blockIdx.y;
    const int bx = blockIdx.x;
    const int t0 = bx * 16;
    const int tid = threadIdx.x;
    const int wave = tid >> 6, lane = tid & 63;
    const float4* xb4 = (const float4*)(x + (size_t)b * S * D);
    float4 xr[16];
#pragma unroll
    for (int t = 0; t < 16; ++t) xr[t] = xb4[(size_t)(t0 + t) * 256 + tid];
    // u[b, d-slice] = sum of 16 u_part slices (L2/L3-hot)
    float4 uv = {0.f, 0.f, 0.f, 0.f};
    const float4* up4 = (const float4*)(ws + UPART_OFF);
#pragma unroll
    for (int g = 0; g < 16; ++g) {
        float4 t = up4[(g * 8 + b) * 256 + tid];
        uv.x += t.x; uv.y += t.y; uv.z += t.z; uv.w += t.w;
    }
    __shared__ float part[16][256];
#pragma unroll
    for (int t = 0; t < 16; ++t)
        part[t][tid] = xr[t].x * uv.x + xr[t].y * uv.y + xr[t].z * uv.z + xr[t].w * uv.w;
    __syncthreads();
    __shared__ float s_sc[16];
#pragma unroll
    for (int r = 0; r < 4; ++r) {
        int t = wave * 4 + r;
        float v = part[t][lane] + part[t][lane + 64] + part[t][lane + 128] + part[t][lane + 192];
        v = waveReduceSum(v);
        if (lane == 0) s_sc[t] = v * 0.03125f;  // 1/sqrt(1024)
    }
    __syncthreads();
    // unstable softmax partials: scores ~ N(0,1) -> exp safe in fp32
    float p[16], l = 0.f;
#pragma unroll
    for (int t = 0; t < 16; ++t) {
        p[t] = __expf(s_sc[t]);
        l += p[t];
    }
    float4 wl = {0.f, 0.f, 0.f, 0.f};
#pragma unroll
    for (int t = 0; t < 16; ++t) {
        wl.x += p[t] * xr[t].x;
        wl.y += p[t] * xr[t].y;
        wl.z += p[t] * xr[t].z;
        wl.w += p[t] * xr[t].w;
    }
    ((float4*)(ws + NUMP_OFF + (size_t)(bx * 8 + b) * 1024))[tid] = wl;
    if (tid == 0) ws[DENP_OFF + bx * 8 + b] = l;
}

// ---------------- KC: sum 128 partials -> (num/den) @ Wv -> wacc_p atomics ---
// grid 128, block 256. d0=(bid>>2)*32, dp=(bid&3)*256+tid, copy c=(bid>>2)&3.
__global__ void __launch_bounds__(256) kC(const float* __restrict__ Wv,
                                          float* __restrict__ ws) {
    const int tid = threadIdx.x;
    const int bid = blockIdx.x;
    const int d0 = (bid >> 2) * 32;
    const int dp = (bid & 3) * 256 + tid;
    const int c = (bid >> 2) & 3;
    __shared__ float dsm[1024], invden[8], vs[8][32];
    for (int j = tid; j < 1024; j += 256) dsm[j] = ws[DENP_OFF + j];
    __syncthreads();
    if (tid < 8) {
        float s = 0.f;
        for (int pp = 0; pp < 128; ++pp) s += dsm[pp * 8 + tid];
        invden[tid] = 1.f / s;
    }
    __syncthreads();
    {   // vs[b][dd] = (sum of 128 num partials) / den
        int b = tid >> 5, dd = tid & 31;
        float s = 0.f;
#pragma unroll 16
        for (int pp = 0; pp < 128; ++pp)
            s += ws[NUMP_OFF + (size_t)(pp * 8 + b) * 1024 + d0 + dd];
        vs[b][dd] = s * invden[b];
    }
    __syncthreads();
    float acc[8] = {0.f, 0.f, 0.f, 0.f, 0.f, 0.f, 0.f, 0.f};
#pragma unroll 8
    for (int dd = 0; dd < 32; ++dd) {
        float wv = Wv[(size_t)(d0 + dd) * D + dp];
#pragma unroll
        for (int b = 0; b < 8; ++b) acc[b] += vs[b][dd] * wv;
    }
#pragma unroll
    for (int b = 0; b < 8; ++b)
        atomicAdd(ws + WACC_OFF + (size_t)c * 8192 + b * 1024 + dp, acc[b]);
}

// ---------------- KD: LN1 + Wd -> hacc_p atomics (no epilogue) ---------------
// grid 128, block 256. wacc = sum of 4 copies; hacc copy c2=(bid>>2)&3.
__global__ void __launch_bounds__(256) kD(const float* __restrict__ bv,
                                          const float* __restrict__ x,
                                          const float* __restrict__ g1,
                                          const float* __restrict__ b1,
                                          const float* __restrict__ Wd,
                                          float* __restrict__ ws) {
    const int tid = threadIdx.x;
    const int bid = blockIdx.x;
    const int d0 = (bid >> 2) * 32;
    const int dp = (bid & 3) * 256 + tid;
    const int c2 = (bid >> 2) & 3;
    const int wave = tid >> 6, lane = tid & 63;
    __shared__ float sMu[8], sInv[8], vs[8][32];
    {
        const float4* wacc4 = (const float4*)(ws + WACC_OFF);  // 4 x 2048 f4
        const float4* bv4 = (const float4*)bv;
#pragma unroll
        for (int h = 0; h < 2; ++h) {
            int b = wave + h * 4;
            const float4* xb4r = (const float4*)(x + (size_t)b * S * D);
            float s = 0.f, ss = 0.f;
#pragma unroll
            for (int i = 0; i < 4; ++i) {
                int idx = lane + 64 * i;
                float4 wv = wacc4[0 * 2048 + b * 256 + idx];
                float4 w1 = wacc4[1 * 2048 + b * 256 + idx];
                float4 w2 = wacc4[2 * 2048 + b * 256 + idx];
                float4 w3 = wacc4[3 * 2048 + b * 256 + idx];
                float4 bb = bv4[idx];
                float4 xv = xb4r[idx];
                float v0 = wv.x + w1.x + w2.x + w3.x + bb.x + xv.x;
                float v1 = wv.y + w1.y + w2.y + w3.y + bb.y + xv.y;
                float v2 = wv.z + w1.z + w2.z + w3.z + bb.z + xv.z;
                float v3 = wv.w + w1.w + w2.w + w3.w + bb.w + xv.w;
                s += v0 + v1 + v2 + v3;
                ss += v0 * v0 + v1 * v1 + v2 * v2 + v3 * v3;
            }
            s = waveReduceSum(s);
            ss = waveReduceSum(ss);
            if (lane == 0) {
                float mu = s * (1.0f / D);
                sMu[b] = mu;
                sInv[b] = rsqrtf(ss * (1.0f / D) - mu * mu + 1e-5f);
            }
        }
    }
    __syncthreads();
    {
        int b = tid >> 5, dd = tid & 31, d = d0 + dd;
        float v = ws[WACC_OFF + 0 * 8192 + b * 1024 + d] +
                  ws[WACC_OFF + 1 * 8192 + b * 1024 + d] +
                  ws[WACC_OFF + 2 * 8192 + b * 1024 + d] +
                  ws[WACC_OFF + 3 * 8192 + b * 1024 + d] +
                  bv[d] + x[(size_t)b * S * D + d];
        vs[b][dd] = (v - sMu[b]) * sInv[b] * g1[d] + b1[d];
    }
    __syncthreads();
    float acc[8] = {0.f, 0.f, 0.f, 0.f, 0.f, 0.f, 0.f, 0.f};
#pragma unroll 8
    for (int dd = 0; dd < 32; ++dd) {
        float wv = Wd[(size_t)(d0 + dd) * D + dp];
#pragma unroll
        for (int b = 0; b < 8; ++b) acc[b] += vs[b][dd] * wv;
    }
#pragma unroll
    for (int b = 0; b < 8; ++b)
        atomicAdd(ws + HACC_OFF + (size_t)c2 * 8192 + b * 1024 + dp, acc[b]);
}

// ---------------- KE: ln1 recompute + ReLU + LN2 + classifier -> out ---------
// grid 8 (parallel over batches), block 256. Float4 loads throughout.
__global__ void __launch_bounds__(256) kE(const float* __restrict__ bv,
                                          const float* __restrict__ x,
                                          const float* __restrict__ g1,
                                          const float* __restrict__ b1,
                                          const float* __restrict__ bd,
                                          const float* __restrict__ g2,
                                          const float* __restrict__ b2,
                                          const float* __restrict__ Wc,
                                          const float* __restrict__ bc,
                                          const float* __restrict__ ws,
                                          float* __restrict__ out) {
    const int b = blockIdx.x;
    const int tid = threadIdx.x;
    const float4* wacc4 = (const float4*)(ws + WACC_OFF);
    const float4* hacc4 = (const float4*)(ws + HACC_OFF);
    float4 w0 = wacc4[0 * 2048 + b * 256 + tid];
    float4 w1 = wacc4[1 * 2048 + b * 256 + tid];
    float4 w2 = wacc4[2 * 2048 + b * 256 + tid];
    float4 w3 = wacc4[3 * 2048 + b * 256 + tid];
    float4 h0 = hacc4[0 * 2048 + b * 256 + tid];
    float4 h1 = hacc4[1 * 2048 + b * 256 + tid];
    float4 h2 = hacc4[2 * 2048 + b * 256 + tid];
    float4 h3 = hacc4[3 * 2048 + b * 256 + tid];
    float4 bb = ((const float4*)bv)[tid];
    float4 xv = ((const float4*)(x + (size_t)b * S * D))[tid];
    float4 g14 = ((const float4*)g1)[tid];
    float4 b14 = ((const float4*)b1)[tid];
    float4 bd4 = ((const float4*)bd)[tid];
    float4 g24 = ((const float4*)g2)[tid];
    float4 b24 = ((const float4*)b2)[tid];
    float4 wc0 = ((const float4*)Wc)[tid * 2];      // (e0:[w0,w1]), (e1:[w0,w1])
    float4 wc1 = ((const float4*)Wc)[tid * 2 + 1];  // (e2), (e3)
    float4 r;
    r.x = w0.x + w1.x + w2.x + w3.x + bb.x + xv.x;
    r.y = w0.y + w1.y + w2.y + w3.y + bb.y + xv.y;
    r.z = w0.z + w1.z + w2.z + w3.z + bb.z + xv.z;
    r.w = w0.w + w1.w + w2.w + w3.w + bb.w + xv.w;
    float s = blockReduceSum(r.x + r.y + r.z + r.w);
    float ss = blockReduceSum(r.x * r.x + r.y * r.y + r.z * r.z + r.w * r.w);
    float mu1 = s * (1.0f / D);
    float inv1 = rsqrtf(ss * (1.0f / D) - mu1 * mu1 + 1e-5f);
    float4 hs;
    hs.x = fmaxf(h0.x + h1.x + h2.x + h3.x + bd4.x, 0.f) + (r.x - mu1) * inv1 * g14.x + b14.x;
    hs.y = fmaxf(h0.y + h1.y + h2.y + h3.y + bd4.y, 0.f) + (r.y - mu1) * inv1 * g14.y + b14.y;
    hs.z = fmaxf(h0.z + h1.z + h2.z + h3.z + bd4.z, 0.f) + (r.z - mu1) * inv1 * g14.z + b14.z;
    hs.w = fmaxf(h0.w + h1.w + h2.w + h3.w + bd4.w, 0.f) + (r.w - mu1) * inv1 * g14.w + b14.w;
    float s2 = blockReduceSum(hs.x + hs.y + hs.z + hs.w);
    float ss2 = blockReduceSum(hs.x * hs.x + hs.y * hs.y + hs.z * hs.z + hs.w * hs.w);
    float mu2 = s2 * (1.0f / D);
    float inv2 = rsqrtf(ss2 * (1.0f / D) - mu2 * mu2 + 1e-5f);
    float l0 = (hs.x - mu2) * inv2 * g24.x + b24.x;
    float l1 = (hs.y - mu2) * inv2 * g24.y + b24.y;
    float l2v = (hs.z - mu2) * inv2 * g24.z + b24.z;
    float l3 = (hs.w - mu2) * inv2 * g24.w + b24.w;
    float p0 = blockReduceSum(l0 * wc0.x + l1 * wc0.z + l2v * wc1.x + l3 * wc1.z);
    float p1 = blockReduceSum(l0 * wc0.y + l1 * wc0.w + l2v * wc1.y + l3 * wc1.w);
    if (tid == 0) {
        out[b * 2 + 0] = p0 + bc[0];
        out[b * 2 + 1] = p1 + bc[1];
    }
}

extern "C" void kernel_launch(void* const* d_in, const int* in_sizes, int n_in,
                              void* d_out, int out_size, void* d_ws, size_t ws_size,
                              hipStream_t stream) {
    const float* x  = (const float*)d_in[0];
    const float* Wq = (const float*)d_in[1];
    const float* bq = (const float*)d_in[2];
    const float* Wk = (const float*)d_in[3];
    // bk (d_in[4]): constant over t -> cancels in softmax
    const float* Wv = (const float*)d_in[5];
    const float* bv = (const float*)d_in[6];
    const float* Wd = (const float*)d_in[7];
    const float* bd = (const float*)d_in[8];
    const float* g1 = (const float*)d_in[9];
    const float* b1 = (const float*)d_in[10];
    const float* g2 = (const float*)d_in[11];
    const float* b2 = (const float*)d_in[12];
    const float* Wc = (const float*)d_in[13];
    const float* bc = (const float*)d_in[14];
    float* out = (float*)d_out;
    float* ws = (float*)d_ws;

    // KA: merged Wq/Wk front-end -> u_part ; zeroes wacc/hacc
    kA<<<64, 256, 0, stream>>>(x, Wq, bq, Wk, ws);
    // KB: scores + unstable softmax -> NON-ATOMIC num/den partials
    kB<<<dim3(128, 8), 256, 0, stream>>>(x, ws);
    // KC: reduce 128 partials + @Wv -> 4-way privatized wacc
    kC<<<128, 256, 0, stream>>>(Wv, ws);
    // KD: LN1 + @Wd -> 4-way privatized hacc
    kD<<<128, 256, 0, stream>>>(bv, x, g1, b1, Wd, ws);
    // KE: ReLU + LN2 + classifier (parallel over batches)
    kE<<<8, 256, 0, stream>>>(bv, x, g1, b1, bd, g2, b2, Wc, bc, ws, out);
}

// Round 12
// 161.020 us; speedup vs baseline: 1.3929x; 1.0172x over previous
//
#include <hip/hip_runtime.h>
#include <math.h>

#define B 8
#define S 2048
#define D 1024

// ---------------- workspace layout (floats) ----------------
// u_part   [16][8][1024]  : 0        (written whole by KA, read by KU)
// num_part [128][8][1024] : 131072   (written whole by KB, read by KC)
// den_part [128][8]       : 1179648  (written whole by KB, read by KC)
// wacc_p   [4][8][1024]   : 1180672  (zeroed KA, atomic KC, read KD/KE)
// hacc_p   [4][8][1024]   : 1213440  (zeroed KA, atomic KD, read KE)
// u        [8][1024]      : 1246208  (written whole by KU, read by KB)
#define UPART_OFF 0
#define NUMP_OFF  131072
#define DENP_OFF  1179648
#define WACC_OFF  1180672
#define HACC_OFF  1213440
#define U_OFF     1246208
#define ZERO_BEG  1180672
#define ZERO_CNT  65536    // wacc_p + hacc_p contiguous

// ---------------- reduction helpers ----------------
__device__ __forceinline__ float waveReduceSum(float v) {
#pragma unroll
    for (int k = 32; k >= 1; k >>= 1) v += __shfl_xor(v, k, 64);
    return v;
}
__device__ float blockReduceSum(float v) {
    __shared__ float sm[4];
    int lane = threadIdx.x & 63, wid = threadIdx.x >> 6;
    v = waveReduceSum(v);
    __syncthreads();
    if (lane == 0) sm[wid] = v;
    __syncthreads();
    return sm[0] + sm[1] + sm[2] + sm[3];
}

// ---------------- KA: u_part[g][b][d] = Wk[d, j in g] . (x0 Wq[:,g] + bq) ----
// grid 64 = (g=16 j-chunks of 64) x (h=4 d-chunks of 256). block 256.
__global__ void __launch_bounds__(256) kA(const float* __restrict__ x,
                                          const float* __restrict__ Wq,
                                          const float* __restrict__ bq,
                                          const float* __restrict__ Wk,
                                          float* __restrict__ ws) {
    const int tid = threadIdx.x;
    for (int zi = blockIdx.x * 256 + tid; zi < ZERO_CNT; zi += 16384)
        ws[ZERO_BEG + zi] = 0.f;
    const int gi = blockIdx.x >> 2, hi = blockIdx.x & 3;
    __shared__ float xs[8][1024];          // 32 KB
    __shared__ float4 zred4[16][8][16];    // 32 KB: (eg, b, jf)
    __shared__ float zf[8][64];            // 2 KB: finalized z (+bq)
    for (int jj = tid; jj < 2048; jj += 256) {   // 2048 float4 = 8 x 256
        int b = jj >> 8, off = jj & 255;
        ((float4*)xs[b])[off] = ((const float4*)(x + (size_t)b * S * D))[off];
    }
    __syncthreads();
    {   // z partials: 64 independent float4 loads per thread
        const int jf = tid & 15, eg = tid >> 4;
        const float4* wq4 = (const float4*)Wq + gi * 16 + jf;  // row stride 256
        const int e0 = eg * 64;
        float4 az[8];
#pragma unroll
        for (int b = 0; b < 8; ++b) az[b] = make_float4(0.f, 0.f, 0.f, 0.f);
#pragma unroll 8
        for (int e = 0; e < 64; ++e) {
            float4 w = wq4[(size_t)(e0 + e) * 256];
#pragma unroll
            for (int b = 0; b < 8; ++b) {
                float xv = xs[b][e0 + e];
                az[b].x += xv * w.x;
                az[b].y += xv * w.y;
                az[b].z += xv * w.z;
                az[b].w += xv * w.w;
            }
        }
#pragma unroll
        for (int b = 0; b < 8; ++b) zred4[eg][b][jf] = az[b];
    }
    __syncthreads();
    if (tid < 128) {   // reduce 16 e-groups -> zf (+bq)
        int b = tid >> 4, jf = tid & 15;
        float4 s = make_float4(0.f, 0.f, 0.f, 0.f);
#pragma unroll
        for (int g = 0; g < 16; ++g) {
            float4 v = zred4[g][b][jf];
            s.x += v.x; s.y += v.y; s.z += v.z; s.w += v.w;
        }
        float4 bb = ((const float4*)bq)[gi * 16 + jf];
        zf[b][jf * 4 + 0] = s.x + bb.x;
        zf[b][jf * 4 + 1] = s.y + bb.y;
        zf[b][jf * 4 + 2] = s.z + bb.z;
        zf[b][jf * 4 + 3] = s.w + bb.w;
    }
    __syncthreads();
    // u_part: thread owns d = hi*256 + tid; 16 independent float4 Wk loads
    {
        const int d = hi * 256 + tid;
        const float4* wk4 = (const float4*)(Wk + (size_t)d * D + gi * 64);
        float au[8] = {0.f, 0.f, 0.f, 0.f, 0.f, 0.f, 0.f, 0.f};
#pragma unroll
        for (int jq = 0; jq < 16; ++jq) {
            float4 w4 = wk4[jq];
#pragma unroll
            for (int b = 0; b < 8; ++b)
                au[b] += w4.x * zf[b][jq * 4 + 0] + w4.y * zf[b][jq * 4 + 1] +
                         w4.z * zf[b][jq * 4 + 2] + w4.w * zf[b][jq * 4 + 3];
        }
#pragma unroll
        for (int b = 0; b < 8; ++b)
            ws[UPART_OFF + (((size_t)gi * 8 + b) << 10) + d] = au[b];
    }
}

// ---------------- KU: u[b][d] = sum_g u_part[g][b][d] ------------------------
// grid 16 (b x 2 halves), block 128. 16 independent float4 L2-hot loads/thread.
__global__ void __launch_bounds__(128) kU(float* __restrict__ ws) {
    const int b = blockIdx.x >> 1, half = blockIdx.x & 1;
    const int f4 = half * 128 + threadIdx.x;       // 0..255
    const float4* up4 = (const float4*)(ws + UPART_OFF);
    float4 s = make_float4(0.f, 0.f, 0.f, 0.f);
#pragma unroll
    for (int g = 0; g < 16; ++g) {
        float4 v = up4[(g * 8 + b) * 256 + f4];
        s.x += v.x; s.y += v.y; s.z += v.z; s.w += v.w;
    }
    ((float4*)(ws + U_OFF))[b * 256 + f4] = s;
}

// ---------------- KB: scores + unstable softmax -> NON-ATOMIC partials -------
// grid (128, 8), block 256. Block: 16 t's of batch b; exclusively owns
// num_part[bx][b][*] and den_part[bx][b] -> plain stores, zero atomics.
// u read as ONE float4 (pre-reduced by KU).
__global__ void __launch_bounds__(256) kB(const float* __restrict__ x,
                                          float* __restrict__ ws) {
    const int b = blockIdx.y;
    const int bx = blockIdx.x;
    const int t0 = bx * 16;
    const int tid = threadIdx.x;
    const int wave = tid >> 6, lane = tid & 63;
    const float4* xb4 = (const float4*)(x + (size_t)b * S * D);
    float4 uv = ((const float4*)(ws + U_OFF))[b * 256 + tid];
    float4 xr[16];
#pragma unroll
    for (int t = 0; t < 16; ++t) xr[t] = xb4[(size_t)(t0 + t) * 256 + tid];
    __shared__ float part[16][256];
#pragma unroll
    for (int t = 0; t < 16; ++t)
        part[t][tid] = xr[t].x * uv.x + xr[t].y * uv.y + xr[t].z * uv.z + xr[t].w * uv.w;
    __syncthreads();
    __shared__ float s_sc[16];
#pragma unroll
    for (int r = 0; r < 4; ++r) {
        int t = wave * 4 + r;
        float v = part[t][lane] + part[t][lane + 64] + part[t][lane + 128] + part[t][lane + 192];
        v = waveReduceSum(v);
        if (lane == 0) s_sc[t] = v * 0.03125f;  // 1/sqrt(1024)
    }
    __syncthreads();
    // unstable softmax partials: scores ~ N(0,1) -> exp safe in fp32
    float p[16], l = 0.f;
#pragma unroll
    for (int t = 0; t < 16; ++t) {
        p[t] = __expf(s_sc[t]);
        l += p[t];
    }
    float4 wl = {0.f, 0.f, 0.f, 0.f};
#pragma unroll
    for (int t = 0; t < 16; ++t) {
        wl.x += p[t] * xr[t].x;
        wl.y += p[t] * xr[t].y;
        wl.z += p[t] * xr[t].z;
        wl.w += p[t] * xr[t].w;
    }
    ((float4*)(ws + NUMP_OFF + (size_t)(bx * 8 + b) * 1024))[tid] = wl;
    if (tid == 0) ws[DENP_OFF + bx * 8 + b] = l;
}

// ---------------- KC: sum 128 partials -> (num/den) @ Wv -> wacc_p atomics ---
// grid 128, block 256. d0=(bid>>2)*32, dp=(bid&3)*256+tid, copy c=(bid>>2)&3.
__global__ void __launch_bounds__(256) kC(const float* __restrict__ Wv,
                                          float* __restrict__ ws) {
    const int tid = threadIdx.x;
    const int bid = blockIdx.x;
    const int d0 = (bid >> 2) * 32;
    const int dp = (bid & 3) * 256 + tid;
    const int c = (bid >> 2) & 3;
    __shared__ float dsm[1024], invden[8], vs[8][32];
    for (int j = tid; j < 1024; j += 256) dsm[j] = ws[DENP_OFF + j];
    __syncthreads();
    if (tid < 8) {
        float s = 0.f;
        for (int pp = 0; pp < 128; ++pp) s += dsm[pp * 8 + tid];
        invden[tid] = 1.f / s;
    }
    __syncthreads();
    {   // vs[b][dd] = (sum of 128 num partials) / den
        int b = tid >> 5, dd = tid & 31;
        float s = 0.f;
#pragma unroll 16
        for (int pp = 0; pp < 128; ++pp)
            s += ws[NUMP_OFF + (size_t)(pp * 8 + b) * 1024 + d0 + dd];
        vs[b][dd] = s * invden[b];
    }
    __syncthreads();
    float acc[8] = {0.f, 0.f, 0.f, 0.f, 0.f, 0.f, 0.f, 0.f};
#pragma unroll 8
    for (int dd = 0; dd < 32; ++dd) {
        float wv = Wv[(size_t)(d0 + dd) * D + dp];
#pragma unroll
        for (int b = 0; b < 8; ++b) acc[b] += vs[b][dd] * wv;
    }
#pragma unroll
    for (int b = 0; b < 8; ++b)
        atomicAdd(ws + WACC_OFF + (size_t)c * 8192 + b * 1024 + dp, acc[b]);
}

// ---------------- KD: LN1 + Wd -> hacc_p atomics -----------------------------
// grid 128, block 256. wacc = sum of 4 copies; hacc copy c2=(bid>>2)&3.
__global__ void __launch_bounds__(256) kD(const float* __restrict__ bv,
                                          const float* __restrict__ x,
                                          const float* __restrict__ g1,
                                          const float* __restrict__ b1,
                                          const float* __restrict__ Wd,
                                          float* __restrict__ ws) {
    const int tid = threadIdx.x;
    const int bid = blockIdx.x;
    const int d0 = (bid >> 2) * 32;
    const int dp = (bid & 3) * 256 + tid;
    const int c2 = (bid >> 2) & 3;
    const int wave = tid >> 6, lane = tid & 63;
    __shared__ float sMu[8], sInv[8], vs[8][32];
    {
        const float4* wacc4 = (const float4*)(ws + WACC_OFF);  // 4 x 2048 f4
        const float4* bv4 = (const float4*)bv;
#pragma unroll
        for (int h = 0; h < 2; ++h) {
            int b = wave + h * 4;
            const float4* xb4r = (const float4*)(x + (size_t)b * S * D);
            float s = 0.f, ss = 0.f;
#pragma unroll
            for (int i = 0; i < 4; ++i) {
                int idx = lane + 64 * i;
                float4 wv = wacc4[0 * 2048 + b * 256 + idx];
                float4 w1 = wacc4[1 * 2048 + b * 256 + idx];
                float4 w2 = wacc4[2 * 2048 + b * 256 + idx];
                float4 w3 = wacc4[3 * 2048 + b * 256 + idx];
                float4 bb = bv4[idx];
                float4 xv = xb4r[idx];
                float v0 = wv.x + w1.x + w2.x + w3.x + bb.x + xv.x;
                float v1 = wv.y + w1.y + w2.y + w3.y + bb.y + xv.y;
                float v2 = wv.z + w1.z + w2.z + w3.z + bb.z + xv.z;
                float v3 = wv.w + w1.w + w2.w + w3.w + bb.w + xv.w;
                s += v0 + v1 + v2 + v3;
                ss += v0 * v0 + v1 * v1 + v2 * v2 + v3 * v3;
            }
            s = waveReduceSum(s);
            ss = waveReduceSum(ss);
            if (lane == 0) {
                float mu = s * (1.0f / D);
                sMu[b] = mu;
                sInv[b] = rsqrtf(ss * (1.0f / D) - mu * mu + 1e-5f);
            }
        }
    }
    __syncthreads();
    {
        int b = tid >> 5, dd = tid & 31, d = d0 + dd;
        float v = ws[WACC_OFF + 0 * 8192 + b * 1024 + d] +
                  ws[WACC_OFF + 1 * 8192 + b * 1024 + d] +
                  ws[WACC_OFF + 2 * 8192 + b * 1024 + d] +
                  ws[WACC_OFF + 3 * 8192 + b * 1024 + d] +
                  bv[d] + x[(size_t)b * S * D + d];
        vs[b][dd] = (v - sMu[b]) * sInv[b] * g1[d] + b1[d];
    }
    __syncthreads();
    float acc[8] = {0.f, 0.f, 0.f, 0.f, 0.f, 0.f, 0.f, 0.f};
#pragma unroll 8
    for (int dd = 0; dd < 32; ++dd) {
        float wv = Wd[(size_t)(d0 + dd) * D + dp];
#pragma unroll
        for (int b = 0; b < 8; ++b) acc[b] += vs[b][dd] * wv;
    }
#pragma unroll
    for (int b = 0; b < 8; ++b)
        atomicAdd(ws + HACC_OFF + (size_t)c2 * 8192 + b * 1024 + dp, acc[b]);
}

// ---------------- KE: ln1 recompute + ReLU + LN2 + classifier -> out ---------
// grid 8 (parallel over batches), block 256. Float4 loads throughout.
__global__ void __launch_bounds__(256) kE(const float* __restrict__ bv,
                                          const float* __restrict__ x,
                                          const float* __restrict__ g1,
                                          const float* __restrict__ b1,
                                          const float* __restrict__ bd,
                                          const float* __restrict__ g2,
                                          const float* __restrict__ b2,
                                          const float* __restrict__ Wc,
                                          const float* __restrict__ bc,
                                          const float* __restrict__ ws,
                                          float* __restrict__ out) {
    const int b = blockIdx.x;
    const int tid = threadIdx.x;
    const float4* wacc4 = (const float4*)(ws + WACC_OFF);
    const float4* hacc4 = (const float4*)(ws + HACC_OFF);
    float4 w0 = wacc4[0 * 2048 + b * 256 + tid];
    float4 w1 = wacc4[1 * 2048 + b * 256 + tid];
    float4 w2 = wacc4[2 * 2048 + b * 256 + tid];
    float4 w3 = wacc4[3 * 2048 + b * 256 + tid];
    float4 h0 = hacc4[0 * 2048 + b * 256 + tid];
    float4 h1 = hacc4[1 * 2048 + b * 256 + tid];
    float4 h2 = hacc4[2 * 2048 + b * 256 + tid];
    float4 h3 = hacc4[3 * 2048 + b * 256 + tid];
    float4 bb = ((const float4*)bv)[tid];
    float4 xv = ((const float4*)(x + (size_t)b * S * D))[tid];
    float4 g14 = ((const float4*)g1)[tid];
    float4 b14 = ((const float4*)b1)[tid];
    float4 bd4 = ((const float4*)bd)[tid];
    float4 g24 = ((const float4*)g2)[tid];
    float4 b24 = ((const float4*)b2)[tid];
    float4 wc0 = ((const float4*)Wc)[tid * 2];      // (e0:[w0,w1]), (e1:[w0,w1])
    float4 wc1 = ((const float4*)Wc)[tid * 2 + 1];  // (e2), (e3)
    float4 r;
    r.x = w0.x + w1.x + w2.x + w3.x + bb.x + xv.x;
    r.y = w0.y + w1.y + w2.y + w3.y + bb.y + xv.y;
    r.z = w0.z + w1.z + w2.z + w3.z + bb.z + xv.z;
    r.w = w0.w + w1.w + w2.w + w3.w + bb.w + xv.w;
    float s = blockReduceSum(r.x + r.y + r.z + r.w);
    float ss = blockReduceSum(r.x * r.x + r.y * r.y + r.z * r.z + r.w * r.w);
    float mu1 = s * (1.0f / D);
    float inv1 = rsqrtf(ss * (1.0f / D) - mu1 * mu1 + 1e-5f);
    float4 hs;
    hs.x = fmaxf(h0.x + h1.x + h2.x + h3.x + bd4.x, 0.f) + (r.x - mu1) * inv1 * g14.x + b14.x;
    hs.y = fmaxf(h0.y + h1.y + h2.y + h3.y + bd4.y, 0.f) + (r.y - mu1) * inv1 * g14.y + b14.y;
    hs.z = fmaxf(h0.z + h1.z + h2.z + h3.z + bd4.z, 0.f) + (r.z - mu1) * inv1 * g14.z + b14.z;
    hs.w = fmaxf(h0.w + h1.w + h2.w + h3.w + bd4.w, 0.f) + (r.w - mu1) * inv1 * g14.w + b14.w;
    float s2 = blockReduceSum(hs.x + hs.y + hs.z + hs.w);
    float ss2 = blockReduceSum(hs.x * hs.x + hs.y * hs.y + hs.z * hs.z + hs.w * hs.w);
    float mu2 = s2 * (1.0f / D);
    float inv2 = rsqrtf(ss2 * (1.0f / D) - mu2 * mu2 + 1e-5f);
    float l0 = (hs.x - mu2) * inv2 * g24.x + b24.x;
    float l1 = (hs.y - mu2) * inv2 * g24.y + b24.y;
    float l2v = (hs.z - mu2) * inv2 * g24.z + b24.z;
    float l3 = (hs.w - mu2) * inv2 * g24.w + b24.w;
    float p0 = blockReduceSum(l0 * wc0.x + l1 * wc0.z + l2v * wc1.x + l3 * wc1.z);
    float p1 = blockReduceSum(l0 * wc0.y + l1 * wc0.w + l2v * wc1.y + l3 * wc1.w);
    if (tid == 0) {
        out[b * 2 + 0] = p0 + bc[0];
        out[b * 2 + 1] = p1 + bc[1];
    }
}

extern "C" void kernel_launch(void* const* d_in, const int* in_sizes, int n_in,
                              void* d_out, int out_size, void* d_ws, size_t ws_size,
                              hipStream_t stream) {
    const float* x  = (const float*)d_in[0];
    const float* Wq = (const float*)d_in[1];
    const float* bq = (const float*)d_in[2];
    const float* Wk = (const float*)d_in[3];
    // bk (d_in[4]): constant over t -> cancels in softmax
    const float* Wv = (const float*)d_in[5];
    const float* bv = (const float*)d_in[6];
    const float* Wd = (const float*)d_in[7];
    const float* bd = (const float*)d_in[8];
    const float* g1 = (const float*)d_in[9];
    const float* b1 = (const float*)d_in[10];
    const float* g2 = (const float*)d_in[11];
    const float* b2 = (const float*)d_in[12];
    const float* Wc = (const float*)d_in[13];
    const float* bc = (const float*)d_in[14];
    float* out = (float*)d_out;
    float* ws = (float*)d_ws;

    // KA: merged Wq/Wk front-end -> u_part ; zeroes wacc/hacc
    kA<<<64, 256, 0, stream>>>(x, Wq, bq, Wk, ws);
    // KU: u_part -> u (pre-reduction, L2-hot)
    kU<<<16, 128, 0, stream>>>(ws);
    // KB: scores + unstable softmax -> NON-ATOMIC num/den partials
    kB<<<dim3(128, 8), 256, 0, stream>>>(x, ws);
    // KC: reduce 128 partials + @Wv -> 4-way privatized wacc
    kC<<<128, 256, 0, stream>>>(Wv, ws);
    // KD: LN1 + @Wd -> 4-way privatized hacc
    kD<<<128, 256, 0, stream>>>(bv, x, g1, b1, Wd, ws);
    // KE: ReLU + LN2 + classifier (parallel over batches)
    kE<<<8, 256, 0, stream>>>(bv, x, g1, b1, bd, g2, b2, Wc, bc, ws, out);
}

// Round 13
// 152.933 us; speedup vs baseline: 1.4666x; 1.0529x over previous
//
#include <hip/hip_runtime.h>
#include <math.h>

#define B 8
#define S 2048
#define D 1024

// ---------------- workspace layout (floats) ----------------
// z        [8][1024]      : 0        (written whole by KZ, read by KW)
// u        [8][1024]      : 8192     (written whole by KW, read by KB)
// num_part [128][8][1024] : 16384    (written whole by KB, read by KC)
// den_part [128][8]       : 1064960  (written whole by KB, read by KC)
// wacc_p   [4][8][1024]   : 1065984  (zeroed KZ, atomic KC, read KS/KD/KE)
// hacc_p   [4][8][1024]   : 1098752  (zeroed KZ, atomic KD, read KE)
// sMu[8], sInv[8]         : 1131520  (written whole by KS, read by KD)
#define Z_OFF     0
#define U_OFF     8192
#define NUMP_OFF  16384
#define DENP_OFF  1064960
#define WACC_OFF  1065984
#define HACC_OFF  1098752
#define SMU_OFF   1131520
#define SINV_OFF  1131528
#define ZERO_BEG  1065984
#define ZERO_CNT  65536    // wacc_p + hacc_p contiguous

// ---------------- reduction helpers ----------------
__device__ __forceinline__ float waveReduceSum(float v) {
#pragma unroll
    for (int k = 32; k >= 1; k >>= 1) v += __shfl_xor(v, k, 64);
    return v;
}
__device__ float blockReduceSum(float v) {
    __shared__ float sm[4];
    int lane = threadIdx.x & 63, wid = threadIdx.x >> 6;
    v = waveReduceSum(v);
    __syncthreads();
    if (lane == 0) sm[wid] = v;
    __syncthreads();
    return sm[0] + sm[1] + sm[2] + sm[3];
}

// ---------------- KZ: z = x0 @ Wq + bq (round-4 k1, vectorized, proven) ------
// grid 64, block 256. Block owns a 16-wide j chunk (4 float4 columns).
// Threads: jpf = tid&3 (float4 column), kg = tid>>2 (64 k-groups of 16).
// Also zeroes wacc_p + hacc_p (65536 floats, 4 per thread).
__global__ void __launch_bounds__(256) kZ(const float* __restrict__ x,
                                          const float* __restrict__ Wq,
                                          const float* __restrict__ bq,
                                          float* __restrict__ ws) {
    const int tid = threadIdx.x;
    {
        int zi = blockIdx.x * 256 + tid;
#pragma unroll
        for (int r = 0; r < 4; ++r) ws[ZERO_BEG + zi + r * 16384] = 0.f;
    }
    float* z = ws + Z_OFF;
    const int dp0 = blockIdx.x * 16;
    const int dpf = tid & 3;   // float4 column within the 16-wide chunk
    const int kg = tid >> 2;   // 64 k-groups of 16
    __shared__ float xs[8][1024];        // 32 KB (aliased as redA after use)
    __shared__ float4 redB[8 * 4 * 8];   // 4 KB (kh, dpf, b)
    for (int j = tid; j < 2048; j += 256) {  // 2048 float4 = 8 rows x 256
        int b = j >> 8, off = j & 255;
        ((float4*)xs[b])[off] = ((const float4*)(x + (size_t)b * S * D))[off];
    }
    __syncthreads();
    const float4* Wq4 = (const float4*)Wq + (dp0 >> 2) + dpf;  // row stride 256
    float4 acc4[8];
#pragma unroll
    for (int b = 0; b < 8; ++b) acc4[b] = make_float4(0.f, 0.f, 0.f, 0.f);
    const int k0 = kg * 16;
#pragma unroll
    for (int i = 0; i < 16; ++i) {
        int k = k0 + i;
        float4 w4 = Wq4[(size_t)k * 256];
#pragma unroll
        for (int b = 0; b < 8; ++b) {
            float xv = xs[b][k];
            acc4[b].x += xv * w4.x;
            acc4[b].y += xv * w4.y;
            acc4[b].z += xv * w4.z;
            acc4[b].w += xv * w4.w;
        }
    }
    __syncthreads();             // all xs reads done before aliasing as redA
    float4* redA = (float4*)xs;  // 2048 float4 = 32 KB, exact fit
#pragma unroll
    for (int b = 0; b < 8; ++b) redA[(kg * 4 + dpf) * 8 + b] = acc4[b];
    __syncthreads();
    {   // stage A: 256 threads, each sums 8 kg-partials
        int b = tid & 7, dpf2 = (tid >> 3) & 3, kh = tid >> 5;
        float4 s = make_float4(0.f, 0.f, 0.f, 0.f);
#pragma unroll
        for (int g = 0; g < 8; ++g) {
            float4 v = redA[((kh * 8 + g) * 4 + dpf2) * 8 + b];
            s.x += v.x; s.y += v.y; s.z += v.z; s.w += v.w;
        }
        redB[(kh * 4 + dpf2) * 8 + b] = s;
    }
    __syncthreads();
    if (tid < 32) {  // stage B: 32 outputs (8 b x 4 float4 columns)
        int b = tid & 7, dpf2 = tid >> 3;
        float4 s = make_float4(0.f, 0.f, 0.f, 0.f);
#pragma unroll
        for (int g = 0; g < 8; ++g) {
            float4 v = redB[(g * 4 + dpf2) * 8 + b];
            s.x += v.x; s.y += v.y; s.z += v.z; s.w += v.w;
        }
        const float4 bb = ((const float4*)bq)[(dp0 >> 2) + dpf2];
        float4 o;
        o.x = s.x + bb.x; o.y = s.y + bb.y; o.z = s.z + bb.z; o.w = s.w + bb.w;
        ((float4*)(z + (size_t)b * D + dp0))[dpf2] = o;
    }
}

// ---------------- KW: u[b,row] = Wk[row,:] . z[b,:] (round-4 k2, proven) -----
// grid 256, block 256. One wave per row; coalesced float4 Wk reads.
__global__ void __launch_bounds__(256) kW(const float* __restrict__ Wk,
                                          float* __restrict__ ws) {
    const float* z = ws + Z_OFF;
    float* u = ws + U_OFF;
    int wid = (blockIdx.x * 256 + threadIdx.x) >> 6;  // row 0..1023
    int lane = threadIdx.x & 63;
    const float4* Wk4 = (const float4*)(Wk + (size_t)wid * D);
    const float4* z4 = (const float4*)z;
    float acc[8] = {0.f, 0.f, 0.f, 0.f, 0.f, 0.f, 0.f, 0.f};
#pragma unroll
    for (int i = 0; i < 4; ++i) {
        float4 wv = Wk4[lane + 64 * i];
#pragma unroll
        for (int b = 0; b < 8; ++b) {
            float4 qv = z4[b * 256 + lane + 64 * i];
            acc[b] += wv.x * qv.x + wv.y * qv.y + wv.z * qv.z + wv.w * qv.w;
        }
    }
#pragma unroll
    for (int b = 0; b < 8; ++b) {
        float v = waveReduceSum(acc[b]);
        if (lane == 0) u[b * D + wid] = v;
    }
}

// ---------------- KB: scores + unstable softmax -> NON-ATOMIC partials -------
// grid (128, 8), block 256. Block: 16 t's of batch b; exclusively owns
// num_part[bx][b][*] and den_part[bx][b] -> plain stores, zero atomics.
__global__ void __launch_bounds__(256) kB(const float* __restrict__ x,
                                          float* __restrict__ ws) {
    const int b = blockIdx.y;
    const int bx = blockIdx.x;
    const int t0 = bx * 16;
    const int tid = threadIdx.x;
    const int wave = tid >> 6, lane = tid & 63;
    const float4* xb4 = (const float4*)(x + (size_t)b * S * D);
    float4 uv = ((const float4*)(ws + U_OFF))[b * 256 + tid];
    float4 xr[16];
#pragma unroll
    for (int t = 0; t < 16; ++t) xr[t] = xb4[(size_t)(t0 + t) * 256 + tid];
    __shared__ float part[16][256];
#pragma unroll
    for (int t = 0; t < 16; ++t)
        part[t][tid] = xr[t].x * uv.x + xr[t].y * uv.y + xr[t].z * uv.z + xr[t].w * uv.w;
    __syncthreads();
    __shared__ float s_sc[16];
#pragma unroll
    for (int r = 0; r < 4; ++r) {
        int t = wave * 4 + r;
        float v = part[t][lane] + part[t][lane + 64] + part[t][lane + 128] + part[t][lane + 192];
        v = waveReduceSum(v);
        if (lane == 0) s_sc[t] = v * 0.03125f;  // 1/sqrt(1024)
    }
    __syncthreads();
    // unstable softmax partials: scores ~ N(0,1) -> exp safe in fp32
    float p[16], l = 0.f;
#pragma unroll
    for (int t = 0; t < 16; ++t) {
        p[t] = __expf(s_sc[t]);
        l += p[t];
    }
    float4 wl = {0.f, 0.f, 0.f, 0.f};
#pragma unroll
    for (int t = 0; t < 16; ++t) {
        wl.x += p[t] * xr[t].x;
        wl.y += p[t] * xr[t].y;
        wl.z += p[t] * xr[t].z;
        wl.w += p[t] * xr[t].w;
    }
    ((float4*)(ws + NUMP_OFF + (size_t)(bx * 8 + b) * 1024))[tid] = wl;
    if (tid == 0) ws[DENP_OFF + bx * 8 + b] = l;
}

// ---------------- KC: sum 128 partials (float4) -> @Wv -> wacc_p atomics -----
// grid 128, block 256. d0=(bid>>2)*32, dp=(bid&3)*256+tid, copy c=(bid>>2)&3.
// Partial sum vectorized: thread (pg=tid>>6, f4o=tid&63) does 32 float4 loads.
__global__ void __launch_bounds__(256) kC(const float* __restrict__ Wv,
                                          float* __restrict__ ws) {
    const int tid = threadIdx.x;
    const int bid = blockIdx.x;
    const int d0 = (bid >> 2) * 32;
    const int dp = (bid & 3) * 256 + tid;
    const int c = (bid >> 2) & 3;
    __shared__ float dsm[1024], invden[8], vs[8][32];
    __shared__ float4 red4[4][64];
    for (int j = tid; j < 1024; j += 256) dsm[j] = ws[DENP_OFF + j];
    {   // vectorized num partial-sum: 32 independent float4 loads
        const int f4o = tid & 63, pg = tid >> 6;
        const int b = f4o >> 3, f8 = f4o & 7;
        const float4* np4 = (const float4*)(ws + NUMP_OFF);
        const size_t base = (size_t)(d0 >> 2) + f8;
        float4 s4 = make_float4(0.f, 0.f, 0.f, 0.f);
#pragma unroll 8
        for (int i = 0; i < 32; ++i) {
            int pp = pg * 32 + i;
            float4 v = np4[(size_t)(pp * 8 + b) * 256 + base];
            s4.x += v.x; s4.y += v.y; s4.z += v.z; s4.w += v.w;
        }
        red4[pg][f4o] = s4;
    }
    __syncthreads();
    if (tid < 8) {
        float s = 0.f;
        for (int pp = 0; pp < 128; ++pp) s += dsm[pp * 8 + tid];
        invden[tid] = 1.f / s;
    }
    __syncthreads();
    if (tid < 64) {
        float4 a0 = red4[0][tid], a1 = red4[1][tid];
        float4 a2 = red4[2][tid], a3 = red4[3][tid];
        int b2 = tid >> 3, f82 = tid & 7;
        float inv = invden[b2];
        vs[b2][f82 * 4 + 0] = (a0.x + a1.x + a2.x + a3.x) * inv;
        vs[b2][f82 * 4 + 1] = (a0.y + a1.y + a2.y + a3.y) * inv;
        vs[b2][f82 * 4 + 2] = (a0.z + a1.z + a2.z + a3.z) * inv;
        vs[b2][f82 * 4 + 3] = (a0.w + a1.w + a2.w + a3.w) * inv;
    }
    __syncthreads();
    float acc[8] = {0.f, 0.f, 0.f, 0.f, 0.f, 0.f, 0.f, 0.f};
#pragma unroll 8
    for (int dd = 0; dd < 32; ++dd) {
        float wv = Wv[(size_t)(d0 + dd) * D + dp];
#pragma unroll
        for (int b = 0; b < 8; ++b) acc[b] += vs[b][dd] * wv;
    }
#pragma unroll
    for (int b = 0; b < 8; ++b)
        atomicAdd(ws + WACC_OFF + (size_t)c * 8192 + b * 1024 + dp, acc[b]);
}

// ---------------- KS: LN1 stats (mu, inv) per batch -> ws --------------------
// grid 8, block 256. One block per batch; float4 loads.
__global__ void __launch_bounds__(256) kS(const float* __restrict__ bv,
                                          const float* __restrict__ x,
                                          float* __restrict__ ws) {
    const int b = blockIdx.x;
    const int tid = threadIdx.x;
    const float4* wacc4 = (const float4*)(ws + WACC_OFF);
    float4 w0 = wacc4[0 * 2048 + b * 256 + tid];
    float4 w1 = wacc4[1 * 2048 + b * 256 + tid];
    float4 w2 = wacc4[2 * 2048 + b * 256 + tid];
    float4 w3 = wacc4[3 * 2048 + b * 256 + tid];
    float4 bb = ((const float4*)bv)[tid];
    float4 xv = ((const float4*)(x + (size_t)b * S * D))[tid];
    float4 r;
    r.x = w0.x + w1.x + w2.x + w3.x + bb.x + xv.x;
    r.y = w0.y + w1.y + w2.y + w3.y + bb.y + xv.y;
    r.z = w0.z + w1.z + w2.z + w3.z + bb.z + xv.z;
    r.w = w0.w + w1.w + w2.w + w3.w + bb.w + xv.w;
    float s = blockReduceSum(r.x + r.y + r.z + r.w);
    float ss = blockReduceSum(r.x * r.x + r.y * r.y + r.z * r.z + r.w * r.w);
    if (tid == 0) {
        float mu = s * (1.0f / D);
        ws[SMU_OFF + b] = mu;
        ws[SINV_OFF + b] = rsqrtf(ss * (1.0f / D) - mu * mu + 1e-5f);
    }
}

// ---------------- KD: LN1 apply + Wd -> hacc_p atomics (stats from KS) -------
// grid 128, block 256. wacc = sum of 4 copies; hacc copy c2=(bid>>2)&3.
__global__ void __launch_bounds__(256) kD(const float* __restrict__ bv,
                                          const float* __restrict__ x,
                                          const float* __restrict__ g1,
                                          const float* __restrict__ b1,
                                          const float* __restrict__ Wd,
                                          float* __restrict__ ws) {
    const int tid = threadIdx.x;
    const int bid = blockIdx.x;
    const int d0 = (bid >> 2) * 32;
    const int dp = (bid & 3) * 256 + tid;
    const int c2 = (bid >> 2) & 3;
    __shared__ float sMu[8], sInv[8], vs[8][32];
    if (tid < 8) {
        sMu[tid] = ws[SMU_OFF + tid];
        sInv[tid] = ws[SINV_OFF + tid];
    }
    __syncthreads();
    {
        int b = tid >> 5, dd = tid & 31, d = d0 + dd;
        float v = ws[WACC_OFF + 0 * 8192 + b * 1024 + d] +
                  ws[WACC_OFF + 1 * 8192 + b * 1024 + d] +
                  ws[WACC_OFF + 2 * 8192 + b * 1024 + d] +
                  ws[WACC_OFF + 3 * 8192 + b * 1024 + d] +
                  bv[d] + x[(size_t)b * S * D + d];
        vs[b][dd] = (v - sMu[b]) * sInv[b] * g1[d] + b1[d];
    }
    __syncthreads();
    float acc[8] = {0.f, 0.f, 0.f, 0.f, 0.f, 0.f, 0.f, 0.f};
#pragma unroll 8
    for (int dd = 0; dd < 32; ++dd) {
        float wv = Wd[(size_t)(d0 + dd) * D + dp];
#pragma unroll
        for (int b = 0; b < 8; ++b) acc[b] += vs[b][dd] * wv;
    }
#pragma unroll
    for (int b = 0; b < 8; ++b)
        atomicAdd(ws + HACC_OFF + (size_t)c2 * 8192 + b * 1024 + dp, acc[b]);
}

// ---------------- KE: ln1 recompute + ReLU + LN2 + classifier -> out ---------
// grid 8 (parallel over batches), block 256. Float4 loads throughout.
__global__ void __launch_bounds__(256) kE(const float* __restrict__ bv,
                                          const float* __restrict__ x,
                                          const float* __restrict__ g1,
                                          const float* __restrict__ b1,
                                          const float* __restrict__ bd,
                                          const float* __restrict__ g2,
                                          const float* __restrict__ b2,
                                          const float* __restrict__ Wc,
                                          const float* __restrict__ bc,
                                          const float* __restrict__ ws,
                                          float* __restrict__ out) {
    const int b = blockIdx.x;
    const int tid = threadIdx.x;
    const float4* wacc4 = (const float4*)(ws + WACC_OFF);
    const float4* hacc4 = (const float4*)(ws + HACC_OFF);
    float4 w0 = wacc4[0 * 2048 + b * 256 + tid];
    float4 w1 = wacc4[1 * 2048 + b * 256 + tid];
    float4 w2 = wacc4[2 * 2048 + b * 256 + tid];
    float4 w3 = wacc4[3 * 2048 + b * 256 + tid];
    float4 h0 = hacc4[0 * 2048 + b * 256 + tid];
    float4 h1 = hacc4[1 * 2048 + b * 256 + tid];
    float4 h2 = hacc4[2 * 2048 + b * 256 + tid];
    float4 h3 = hacc4[3 * 2048 + b * 256 + tid];
    float4 bb = ((const float4*)bv)[tid];
    float4 xv = ((const float4*)(x + (size_t)b * S * D))[tid];
    float4 g14 = ((const float4*)g1)[tid];
    float4 b14 = ((const float4*)b1)[tid];
    float4 bd4 = ((const float4*)bd)[tid];
    float4 g24 = ((const float4*)g2)[tid];
    float4 b24 = ((const float4*)b2)[tid];
    float4 wc0 = ((const float4*)Wc)[tid * 2];      // (e0:[w0,w1]), (e1:[w0,w1])
    float4 wc1 = ((const float4*)Wc)[tid * 2 + 1];  // (e2), (e3)
    float4 r;
    r.x = w0.x + w1.x + w2.x + w3.x + bb.x + xv.x;
    r.y = w0.y + w1.y + w2.y + w3.y + bb.y + xv.y;
    r.z = w0.z + w1.z + w2.z + w3.z + bb.z + xv.z;
    r.w = w0.w + w1.w + w2.w + w3.w + bb.w + xv.w;
    float s = blockReduceSum(r.x + r.y + r.z + r.w);
    float ss = blockReduceSum(r.x * r.x + r.y * r.y + r.z * r.z + r.w * r.w);
    float mu1 = s * (1.0f / D);
    float inv1 = rsqrtf(ss * (1.0f / D) - mu1 * mu1 + 1e-5f);
    float4 hs;
    hs.x = fmaxf(h0.x + h1.x + h2.x + h3.x + bd4.x, 0.f) + (r.x - mu1) * inv1 * g14.x + b14.x;
    hs.y = fmaxf(h0.y + h1.y + h2.y + h3.y + bd4.y, 0.f) + (r.y - mu1) * inv1 * g14.y + b14.y;
    hs.z = fmaxf(h0.z + h1.z + h2.z + h3.z + bd4.z, 0.f) + (r.z - mu1) * inv1 * g14.z + b14.z;
    hs.w = fmaxf(h0.w + h1.w + h2.w + h3.w + bd4.w, 0.f) + (r.w - mu1) * inv1 * g14.w + b14.w;
    float s2 = blockReduceSum(hs.x + hs.y + hs.z + hs.w);
    float ss2 = blockReduceSum(hs.x * hs.x + hs.y * hs.y + hs.z * hs.z + hs.w * hs.w);
    float mu2 = s2 * (1.0f / D);
    float inv2 = rsqrtf(ss2 * (1.0f / D) - mu2 * mu2 + 1e-5f);
    float l0 = (hs.x - mu2) * inv2 * g24.x + b24.x;
    float l1 = (hs.y - mu2) * inv2 * g24.y + b24.y;
    float l2v = (hs.z - mu2) * inv2 * g24.z + b24.z;
    float l3 = (hs.w - mu2) * inv2 * g24.w + b24.w;
    float p0 = blockReduceSum(l0 * wc0.x + l1 * wc0.z + l2v * wc1.x + l3 * wc1.z);
    float p1 = blockReduceSum(l0 * wc0.y + l1 * wc0.w + l2v * wc1.y + l3 * wc1.w);
    if (tid == 0) {
        out[b * 2 + 0] = p0 + bc[0];
        out[b * 2 + 1] = p1 + bc[1];
    }
}

extern "C" void kernel_launch(void* const* d_in, const int* in_sizes, int n_in,
                              void* d_out, int out_size, void* d_ws, size_t ws_size,
                              hipStream_t stream) {
    const float* x  = (const float*)d_in[0];
    const float* Wq = (const float*)d_in[1];
    const float* bq = (const float*)d_in[2];
    const float* Wk = (const float*)d_in[3];
    // bk (d_in[4]): constant over t -> cancels in softmax
    const float* Wv = (const float*)d_in[5];
    const float* bv = (const float*)d_in[6];
    const float* Wd = (const float*)d_in[7];
    const float* bd = (const float*)d_in[8];
    const float* g1 = (const float*)d_in[9];
    const float* b1 = (const float*)d_in[10];
    const float* g2 = (const float*)d_in[11];
    const float* b2 = (const float*)d_in[12];
    const float* Wc = (const float*)d_in[13];
    const float* bc = (const float*)d_in[14];
    float* out = (float*)d_out;
    float* ws = (float*)d_ws;

    // KZ: z = x0 @ Wq + bq ; zeroes wacc/hacc
    kZ<<<64, 256, 0, stream>>>(x, Wq, bq, ws);
    // KW: u = Wk @ z (one wave per row, coalesced)
    kW<<<256, 256, 0, stream>>>(Wk, ws);
    // KB: scores + unstable softmax -> NON-ATOMIC num/den partials
    kB<<<dim3(128, 8), 256, 0, stream>>>(x, ws);
    // KC: float4 partial reduction + @Wv -> 4-way privatized wacc
    kC<<<128, 256, 0, stream>>>(Wv, ws);
    // KS: LN1 stats once (grid 8)
    kS<<<8, 256, 0, stream>>>(bv, x, ws);
    // KD: LN1 apply + @Wd -> 4-way privatized hacc
    kD<<<128, 256, 0, stream>>>(bv, x, g1, b1, Wd, ws);
    // KE: ReLU + LN2 + classifier (parallel over batches)
    kE<<<8, 256, 0, stream>>>(bv, x, g1, b1, bd, g2, b2, Wc, bc, ws, out);
}